// Round 1
// baseline (268.053 us; speedup 1.0000x reference)
//
#include <hip/hip_runtime.h>
#include <stdint.h>

#define B_ 2
#define S_ 2048
#define D_ 1024
#define H_ 16
#define DK_ 64

typedef __attribute__((ext_vector_type(8))) short short8;   // 8 x bf16 (raw bits)
typedef __attribute__((ext_vector_type(4))) float f32x4;

__device__ __forceinline__ short f2bf(float f) {
    uint32_t u = __float_as_uint(f);
    return (short)((u + 0x7FFFu + ((u >> 16) & 1u)) >> 16);
}

#define GLOAD16(gptr, lptr)                                                      \
    __builtin_amdgcn_global_load_lds(                                            \
        (const __attribute__((address_space(1))) void*)(gptr),                   \
        (__attribute__((address_space(3))) void*)(lptr), 16, 0, 0)

// ---------------- cast f32 -> bf16 (8 elems/thread) ----------------
__global__ __launch_bounds__(256) void cast_kernel(const float* __restrict__ in,
                                                   short* __restrict__ out, int n8) {
    int i = blockIdx.x * 256 + threadIdx.x;
    if (i >= n8) return;
    const float4* p = ((const float4*)in) + (size_t)i * 2;
    float4 a = p[0], b = p[1];
    short8 o;
    o[0] = f2bf(a.x); o[1] = f2bf(a.y); o[2] = f2bf(a.z); o[3] = f2bf(a.w);
    o[4] = f2bf(b.x); o[5] = f2bf(b.y); o[6] = f2bf(b.z); o[7] = f2bf(b.w);
    *(((short8*)out) + i) = o;
}

// ---------------- mask int32 -> bit-packed ----------------
__global__ __launch_bounds__(256) void pack_mask(const int* __restrict__ mask,
                                                 uint32_t* __restrict__ packed) {
    size_t t = (size_t)blockIdx.x * 256 + threadIdx.x;
    bool bit = (mask[t] != 0);
    unsigned long long bal = __ballot(bit);
    int lane = threadIdx.x & 63;
    size_t widx = t >> 5;
    if (lane == 0) packed[widx] = (uint32_t)bal;
    else if (lane == 32) packed[widx] = (uint32_t)(bal >> 32);
}

// ---------------- GEMM: C[M,N] = A[M,K](bf16) * W[N,K]^T(bf16) ----------------
// m97 structure: 128x128 tile, BK=32, 4 waves (2x2), global_load_lds w=16, linear LDS.
template<int F32OUT>
__global__ __launch_bounds__(256) void gemm_nt(const short* __restrict__ A,
                                               const short* __restrict__ W,
                                               void* __restrict__ C,
                                               int M, int N, int K) {
    __shared__ short As[128 * 32];
    __shared__ short Bs[128 * 32];
    const int tid = threadIdx.x;
    const int lane = tid & 63;
    const int w = tid >> 6;
    const int wm = w >> 1, wn = w & 1;
    const int mBase = blockIdx.y * 128, nBase = blockIdx.x * 128;

    f32x4 acc[4][4];
#pragma unroll
    for (int i = 0; i < 4; i++)
#pragma unroll
        for (int j = 0; j < 4; j++) acc[i][j] = (f32x4)0.f;

    const int srow = lane >> 2;   // row within 16-row segment
    const int sslot = lane & 3;   // 16B slot within 64B row

    for (int k0 = 0; k0 < K; k0 += 32) {
#pragma unroll
        for (int i = 0; i < 2; ++i) {
            int seg = w * 2 + i;                  // wave-uniform
            int row = seg * 16 + srow;
            const short* ga = A + (size_t)(mBase + row) * K + k0 + sslot * 8;
            GLOAD16(ga, (char*)As + seg * 1024);
            const short* gb = W + (size_t)(nBase + row) * K + k0 + sslot * 8;
            GLOAD16(gb, (char*)Bs + seg * 1024);
        }
        asm volatile("s_waitcnt vmcnt(0)" ::: "memory");
        __syncthreads();

        short8 af[4], bfv[4];
#pragma unroll
        for (int mi = 0; mi < 4; mi++)
            af[mi] = *(const short8*)&As[(wm * 64 + mi * 16 + (lane & 15)) * 32 + (lane >> 4) * 8];
#pragma unroll
        for (int ni = 0; ni < 4; ni++)
            bfv[ni] = *(const short8*)&Bs[(wn * 64 + ni * 16 + (lane & 15)) * 32 + (lane >> 4) * 8];
#pragma unroll
        for (int mi = 0; mi < 4; mi++)
#pragma unroll
            for (int ni = 0; ni < 4; ni++)
                acc[mi][ni] = __builtin_amdgcn_mfma_f32_16x16x32_bf16(af[mi], bfv[ni], acc[mi][ni], 0, 0, 0);
        __syncthreads();
    }

#pragma unroll
    for (int mi = 0; mi < 4; mi++)
#pragma unroll
        for (int ni = 0; ni < 4; ni++)
#pragma unroll
            for (int r = 0; r < 4; r++) {
                int row = mBase + wm * 64 + mi * 16 + (lane >> 4) * 4 + r;
                int col = nBase + wn * 64 + ni * 16 + (lane & 15);
                float v = acc[mi][ni][r];
                if (F32OUT) ((float*)C)[(size_t)row * N + col] = v;
                else        ((short*)C)[(size_t)row * N + col] = f2bf(v);
            }
}

// ---------------- V transpose: Vp[b,s,h*64+dk] -> Vt[(b*H+h)*64+dk][s] ----------------
__global__ __launch_bounds__(256) void transpose_v(const short* __restrict__ Vp,
                                                   short* __restrict__ Vt) {
    __shared__ short t[64 * 72];   // pad row to 72 elems (144B) to spread banks
    int bid = blockIdx.x;
    int bh = bid >> 5;             // b*H+h
    int st = bid & 31;
    int b = bh >> 4, h = bh & 15;
    int sBase = st * 64;
    int tid = threadIdx.x;
#pragma unroll
    for (int i = 0; i < 2; i++) {
        int ci = i * 256 + tid;
        int sr = ci >> 3, sl = ci & 7;
        short8 v = *(const short8*)&Vp[(size_t)(b * S_ + sBase + sr) * D_ + h * 64 + sl * 8];
#pragma unroll
        for (int j = 0; j < 8; j++) t[(sl * 8 + j) * 72 + sr] = v[j];
    }
    __syncthreads();
#pragma unroll
    for (int i = 0; i < 2; i++) {
        int ci = i * 256 + tid;
        int dk = ci >> 3, sl = ci & 7;
        short8 o = *(const short8*)&t[dk * 72 + sl * 8];
        *(short8*)&Vt[(size_t)((b * H_ + h) * 64 + dk) * S_ + sBase + sl * 8] = o;
    }
}

// ---------------- flash attention ----------------
// grid (S/64, B*H), 4 waves; wave w owns q rows [qBase+w*16, +16).
__global__ __launch_bounds__(256) void attn_kernel(const short* __restrict__ Qp,
                                                   const short* __restrict__ Kp,
                                                   const short* __restrict__ Vt,
                                                   const uint32_t* __restrict__ mp,
                                                   short* __restrict__ Op) {
    __shared__ short Ks[64 * 64];
    __shared__ short Vs[64 * 64];
    __shared__ short Ps[4][16 * 64];
    const int qt = blockIdx.x;
    const int bh = blockIdx.y;
    const int b = bh >> 4, h = bh & 15;
    const int qBase = qt * 64;
    const int tid = threadIdx.x, lane = tid & 63, w = tid >> 6;
    const int lg = lane >> 4;   // k-group 0..3
    const int li = lane & 15;

    // Q fragments in registers (A-operand rows = li)
    short8 qf[2];
    {
        int qrow = qBase + w * 16 + li;
#pragma unroll
        for (int ks = 0; ks < 2; ks++)
            qf[ks] = *(const short8*)&Qp[(size_t)(b * S_ + qrow) * D_ + h * 64 + lg * 8 + ks * 32];
    }

    float m_r[4], l_r[4];
    f32x4 acc_o[4];
#pragma unroll
    for (int r = 0; r < 4; r++) { m_r[r] = -1e30f; l_r[r] = 0.f; }
#pragma unroll
    for (int g = 0; g < 4; g++) acc_o[g] = (f32x4)0.f;

    for (int kt = 0; kt < S_ / 64; ++kt) {
        const int kBase = kt * 64;
        // stage K-tile and V^T-tile, XOR-swizzled source -> linear LDS writes
#pragma unroll
        for (int i = 0; i < 2; i++) {
            int ci = i * 256 + tid;
            int r = ci >> 3, s = ci & 7;
            int gs = s ^ (r & 7);
            short8 kv = *(const short8*)&Kp[(size_t)(b * S_ + kBase + r) * D_ + h * 64 + gs * 8];
            *(short8*)&Ks[r * 64 + s * 8] = kv;
            short8 vv = *(const short8*)&Vt[(size_t)((b * H_ + h) * 64 + r) * S_ + kBase + gs * 8];
            *(short8*)&Vs[r * 64 + s * 8] = vv;
        }
        __syncthreads();

        // S = Q K^T / 8
        f32x4 sc[4];
#pragma unroll
        for (int nt = 0; nt < 4; nt++) {
            f32x4 c = (f32x4)0.f;
#pragma unroll
            for (int ks = 0; ks < 2; ks++) {
                int rk = nt * 16 + li;
                int slot = (lg + ks * 4) ^ (rk & 7);
                short8 kf = *(const short8*)&Ks[rk * 64 + slot * 8];
                c = __builtin_amdgcn_mfma_f32_16x16x32_bf16(qf[ks], kf, c, 0, 0, 0);
            }
            sc[nt] = c * 0.125f;
        }
        // mask (packed bits)
#pragma unroll
        for (int r = 0; r < 4; r++) {
            int q = qBase + w * 16 + lg * 4 + r;
            uint2 mw = *(const uint2*)&mp[(size_t)(b * S_ + q) * 64 + kt * 2];
#pragma unroll
            for (int nt = 0; nt < 4; nt++) {
                uint32_t wd = (nt < 2) ? mw.x : mw.y;
                int bit = (nt * 16 + li) & 31;
                if (!((wd >> bit) & 1u)) sc[nt][r] = -1e9f;
            }
        }
        // online softmax (row-reduce across the 16-lane group)
        float p[4][4];
#pragma unroll
        for (int r = 0; r < 4; r++) {
            float tm = fmaxf(fmaxf(sc[0][r], sc[1][r]), fmaxf(sc[2][r], sc[3][r]));
#pragma unroll
            for (int off = 1; off < 16; off <<= 1) tm = fmaxf(tm, __shfl_xor(tm, off));
            float mn = fmaxf(m_r[r], tm);
            float alpha = __expf(m_r[r] - mn);
            float ps = 0.f;
#pragma unroll
            for (int nt = 0; nt < 4; nt++) { float e = __expf(sc[nt][r] - mn); p[nt][r] = e; ps += e; }
#pragma unroll
            for (int off = 1; off < 16; off <<= 1) ps += __shfl_xor(ps, off);
            l_r[r] = l_r[r] * alpha + ps;
            m_r[r] = mn;
#pragma unroll
            for (int g = 0; g < 4; g++) acc_o[g][r] *= alpha;
        }
        // P (D-layout) -> per-wave LDS buffer (swizzled), re-read in A-layout
#pragma unroll
        for (int r = 0; r < 4; r++) {
            int row = lg * 4 + r;
#pragma unroll
            for (int nt = 0; nt < 4; nt++) {
                int col = nt * 16 + li;
                Ps[w][row * 64 + (((col >> 3) ^ (row & 7)) * 8) + (col & 7)] = f2bf(p[nt][r]);
            }
        }
        // O += P V
#pragma unroll
        for (int ks = 0; ks < 2; ks++) {
            int slotp = (lg + ks * 4) ^ (li & 7);
            short8 pf = *(const short8*)&Ps[w][li * 64 + slotp * 8];
#pragma unroll
            for (int g = 0; g < 4; g++) {
                int rv = g * 16 + li;
                int slotv = (lg + ks * 4) ^ (rv & 7);
                short8 vf = *(const short8*)&Vs[rv * 64 + slotv * 8];
                acc_o[g] = __builtin_amdgcn_mfma_f32_16x16x32_bf16(pf, vf, acc_o[g], 0, 0, 0);
            }
        }
        __syncthreads();
    }
    // normalize + store
#pragma unroll
    for (int r = 0; r < 4; r++) {
        int q = qBase + w * 16 + lg * 4 + r;
        float inv = 1.f / l_r[r];
#pragma unroll
        for (int g = 0; g < 4; g++)
            Op[(size_t)(b * S_ + q) * D_ + h * 64 + g * 16 + li] = f2bf(acc_o[g][r] * inv);
    }
}

extern "C" void kernel_launch(void* const* d_in, const int* in_sizes, int n_in,
                              void* d_out, int out_size, void* d_ws, size_t ws_size,
                              hipStream_t stream) {
    const float* q  = (const float*)d_in[0];
    const float* k  = (const float*)d_in[1];
    const float* v  = (const float*)d_in[2];
    const int*   mk = (const int*)d_in[3];
    const float* wq = (const float*)d_in[4];
    const float* wk = (const float*)d_in[5];
    const float* wv = (const float*)d_in[6];
    const float* wo = (const float*)d_in[7];

    const size_t SZ = (size_t)B_ * S_ * D_;   // 4194304
    const size_t DD = (size_t)D_ * D_;        // 1048576
    const size_t NEED = (6 * SZ + 4 * DD) * 2 + (size_t)B_ * S_ * 64 * 4;
    if (ws_size < NEED) return;

    short* ws  = (short*)d_ws;
    short* qb  = ws;            // bf16 inputs
    short* kb  = qb + SZ;
    short* vb  = kb + SZ;
    short* wqb = vb + SZ;       // bf16 weights
    short* wkb = wqb + DD;
    short* wvb = wkb + DD;
    short* wob = wvb + DD;
    short* Qp  = wob + DD;      // projections
    short* Kp  = Qp + SZ;
    short* Vp  = Kp + SZ;
    uint32_t* mp = (uint32_t*)(Vp + SZ);
    short* Vtr = qb;            // alias: qb dead after Q-GEMM, transpose runs after
    short* Opx = kb;            // alias: kb dead after K-GEMM, attn runs after

    dim3 blk(256);
    cast_kernel<<<dim3((unsigned)(SZ / 8 / 256)), blk, 0, stream>>>(q, qb, (int)(SZ / 8));
    cast_kernel<<<dim3((unsigned)(SZ / 8 / 256)), blk, 0, stream>>>(k, kb, (int)(SZ / 8));
    cast_kernel<<<dim3((unsigned)(SZ / 8 / 256)), blk, 0, stream>>>(v, vb, (int)(SZ / 8));
    cast_kernel<<<dim3((unsigned)(DD / 8 / 256)), blk, 0, stream>>>(wq, wqb, (int)(DD / 8));
    cast_kernel<<<dim3((unsigned)(DD / 8 / 256)), blk, 0, stream>>>(wk, wkb, (int)(DD / 8));
    cast_kernel<<<dim3((unsigned)(DD / 8 / 256)), blk, 0, stream>>>(wv, wvb, (int)(DD / 8));
    cast_kernel<<<dim3((unsigned)(DD / 8 / 256)), blk, 0, stream>>>(wo, wob, (int)(DD / 8));
    pack_mask<<<dim3((unsigned)((size_t)B_ * S_ * S_ / 256)), blk, 0, stream>>>(mk, mp);

    gemm_nt<0><<<dim3(D_ / 128, B_ * S_ / 128), blk, 0, stream>>>(qb, wqb, Qp, B_ * S_, D_, D_);
    gemm_nt<0><<<dim3(D_ / 128, B_ * S_ / 128), blk, 0, stream>>>(kb, wkb, Kp, B_ * S_, D_, D_);
    gemm_nt<0><<<dim3(D_ / 128, B_ * S_ / 128), blk, 0, stream>>>(vb, wvb, Vp, B_ * S_, D_, D_);

    transpose_v<<<dim3(B_ * H_ * (S_ / 64)), blk, 0, stream>>>(Vp, Vtr);

    attn_kernel<<<dim3(S_ / 64, B_ * H_), blk, 0, stream>>>(Qp, Kp, Vtr, mp, Opx);

    gemm_nt<1><<<dim3(D_ / 128, B_ * S_ / 128), blk, 0, stream>>>(Opx, wob, d_out, B_ * S_, D_, D_);
}

// Round 2
// 223.334 us; speedup vs baseline: 1.2002x; 1.2002x over previous
//
#include <hip/hip_runtime.h>
#include <stdint.h>

#define B_ 2
#define S_ 2048
#define D_ 1024
#define H_ 16
#define DK_ 64

typedef __attribute__((ext_vector_type(8))) short short8;   // 8 x bf16 (raw bits)
typedef __attribute__((ext_vector_type(4))) float f32x4;

__device__ __forceinline__ short f2bf(float f) {
    uint32_t u = __float_as_uint(f);
    return (short)((u + 0x7FFFu + ((u >> 16) & 1u)) >> 16);
}

__device__ __forceinline__ float fexp2(float x) {
    float r;
    asm("v_exp_f32 %0, %1" : "=v"(r) : "v"(x));
    return r;
}

__device__ __forceinline__ uint32_t cvt_pk_bf16(float lo, float hi) {
    uint32_t r;
    asm("v_cvt_pk_bf16_f32 %0, %1, %2" : "=v"(r) : "v"(lo), "v"(hi));
    return r;
}

#define GLOAD16(gptr, lptr)                                                      \
    __builtin_amdgcn_global_load_lds(                                            \
        (const __attribute__((address_space(1))) void*)(gptr),                   \
        (__attribute__((address_space(3))) void*)(lptr), 16, 0, 0)

// ---------------- cast f32 -> bf16: q,k,v merged ----------------
__global__ __launch_bounds__(256) void cast_qkv(const float* __restrict__ a,
                                                const float* __restrict__ b,
                                                const float* __restrict__ c,
                                                short* __restrict__ oa,
                                                short* __restrict__ ob,
                                                short* __restrict__ oc) {
    int bid = blockIdx.x;
    int sel = bid >> 11;                 // 2048 blocks per tensor
    int i = (bid & 2047) * 256 + threadIdx.x;
    const float* in = (sel == 0) ? a : (sel == 1) ? b : c;
    short* out = (sel == 0) ? oa : (sel == 1) ? ob : oc;
    const float4* p = ((const float4*)in) + (size_t)i * 2;
    float4 x = p[0], y = p[1];
    short8 o;
    o[0] = f2bf(x.x); o[1] = f2bf(x.y); o[2] = f2bf(x.z); o[3] = f2bf(x.w);
    o[4] = f2bf(y.x); o[5] = f2bf(y.y); o[6] = f2bf(y.z); o[7] = f2bf(y.w);
    *(((short8*)out) + i) = o;
}

// ---------------- cast f32 -> bf16: 4 weights merged ----------------
__global__ __launch_bounds__(256) void cast_w4(const float* __restrict__ a,
                                               const float* __restrict__ b,
                                               const float* __restrict__ c,
                                               const float* __restrict__ d,
                                               short* __restrict__ oa,
                                               short* __restrict__ ob,
                                               short* __restrict__ oc,
                                               short* __restrict__ od) {
    int bid = blockIdx.x;
    int sel = bid >> 9;                  // 512 blocks per tensor
    int i = (bid & 511) * 256 + threadIdx.x;
    const float* in = (sel == 0) ? a : (sel == 1) ? b : (sel == 2) ? c : d;
    short* out = (sel == 0) ? oa : (sel == 1) ? ob : (sel == 2) ? oc : od;
    const float4* p = ((const float4*)in) + (size_t)i * 2;
    float4 x = p[0], y = p[1];
    short8 o;
    o[0] = f2bf(x.x); o[1] = f2bf(x.y); o[2] = f2bf(x.z); o[3] = f2bf(x.w);
    o[4] = f2bf(y.x); o[5] = f2bf(y.y); o[6] = f2bf(y.z); o[7] = f2bf(y.w);
    *(((short8*)out) + i) = o;
}

// ---------------- mask int32 -> bit-packed ----------------
__global__ __launch_bounds__(256) void pack_mask(const int* __restrict__ mask,
                                                 uint32_t* __restrict__ packed) {
    size_t t = (size_t)blockIdx.x * 256 + threadIdx.x;
    bool bit = (mask[t] != 0);
    unsigned long long bal = __ballot(bit);
    int lane = threadIdx.x & 63;
    size_t widx = t >> 5;
    if (lane == 0) packed[widx] = (uint32_t)bal;
    else if (lane == 32) packed[widx] = (uint32_t)(bal >> 32);
}

// ---------------- GEMM: C[M,N] = A[M,K](bf16) * W[N,K]^T(bf16) ----------------
template<int F32OUT>
__global__ __launch_bounds__(256) void gemm_nt(const short* __restrict__ A,
                                               const short* __restrict__ W,
                                               void* __restrict__ C,
                                               int M, int N, int K) {
    __shared__ short As[128 * 32];
    __shared__ short Bs[128 * 32];
    const int tid = threadIdx.x;
    const int lane = tid & 63;
    const int w = tid >> 6;
    const int wm = w >> 1, wn = w & 1;
    const int mBase = blockIdx.y * 128, nBase = blockIdx.x * 128;

    f32x4 acc[4][4];
#pragma unroll
    for (int i = 0; i < 4; i++)
#pragma unroll
        for (int j = 0; j < 4; j++) acc[i][j] = (f32x4)0.f;

    const int srow = lane >> 2;
    const int sslot = lane & 3;

    for (int k0 = 0; k0 < K; k0 += 32) {
#pragma unroll
        for (int i = 0; i < 2; ++i) {
            int seg = w * 2 + i;
            int row = seg * 16 + srow;
            const short* ga = A + (size_t)(mBase + row) * K + k0 + sslot * 8;
            GLOAD16(ga, (char*)As + seg * 1024);
            const short* gb = W + (size_t)(nBase + row) * K + k0 + sslot * 8;
            GLOAD16(gb, (char*)Bs + seg * 1024);
        }
        asm volatile("s_waitcnt vmcnt(0)" ::: "memory");
        __syncthreads();

        short8 af[4], bfv[4];
#pragma unroll
        for (int mi = 0; mi < 4; mi++)
            af[mi] = *(const short8*)&As[(wm * 64 + mi * 16 + (lane & 15)) * 32 + (lane >> 4) * 8];
#pragma unroll
        for (int ni = 0; ni < 4; ni++)
            bfv[ni] = *(const short8*)&Bs[(wn * 64 + ni * 16 + (lane & 15)) * 32 + (lane >> 4) * 8];
#pragma unroll
        for (int mi = 0; mi < 4; mi++)
#pragma unroll
            for (int ni = 0; ni < 4; ni++)
                acc[mi][ni] = __builtin_amdgcn_mfma_f32_16x16x32_bf16(af[mi], bfv[ni], acc[mi][ni], 0, 0, 0);
        __syncthreads();
    }

#pragma unroll
    for (int mi = 0; mi < 4; mi++)
#pragma unroll
        for (int ni = 0; ni < 4; ni++)
#pragma unroll
            for (int r = 0; r < 4; r++) {
                int row = mBase + wm * 64 + mi * 16 + (lane >> 4) * 4 + r;
                int col = nBase + wn * 64 + ni * 16 + (lane & 15);
                float v = acc[mi][ni][r];
                if (F32OUT) ((float*)C)[(size_t)row * N + col] = v;
                else        ((short*)C)[(size_t)row * N + col] = f2bf(v);
            }
}

// ---------------- V transpose ----------------
__global__ __launch_bounds__(256) void transpose_v(const short* __restrict__ Vp,
                                                   short* __restrict__ Vt) {
    __shared__ short t[64 * 72];
    int bid = blockIdx.x;
    int bh = bid >> 5;
    int st = bid & 31;
    int b = bh >> 4, h = bh & 15;
    int sBase = st * 64;
    int tid = threadIdx.x;
#pragma unroll
    for (int i = 0; i < 2; i++) {
        int ci = i * 256 + tid;
        int sr = ci >> 3, sl = ci & 7;
        short8 v = *(const short8*)&Vp[(size_t)(b * S_ + sBase + sr) * D_ + h * 64 + sl * 8];
#pragma unroll
        for (int j = 0; j < 8; j++) t[(sl * 8 + j) * 72 + sr] = v[j];
    }
    __syncthreads();
#pragma unroll
    for (int i = 0; i < 2; i++) {
        int ci = i * 256 + tid;
        int dk = ci >> 3, sl = ci & 7;
        short8 o = *(const short8*)&t[dk * 72 + sl * 8];
        *(short8*)&Vt[(size_t)((b * H_ + h) * 64 + dk) * S_ + sBase + sl * 8] = o;
    }
}

// ---------------- flash attention (swapped QK^T, in-register softmax) ----------------
// grid (S/64, B*H), 4 waves; wave w owns q rows [qBase+w*16, +16); lane li owns q row li.
__global__ __launch_bounds__(256) void attn_kernel(const short* __restrict__ Qp,
                                                   const short* __restrict__ Kp,
                                                   const short* __restrict__ Vt,
                                                   const uint32_t* __restrict__ mp,
                                                   short* __restrict__ Op) {
    __shared__ short Ks[2][64 * 64];
    __shared__ short Vs[2][64 * 64];
    __shared__ short Ps[4 * 16 * 64];     // per-wave P^T buffer, 16B-slot XOR swizzle
    const int qt = blockIdx.x;
    const int bh = blockIdx.y;
    const int b = bh >> 4, h = bh & 15;
    const int qBase = qt * 64;
    const int tid = threadIdx.x, lane = tid & 63, w = tid >> 6;
    const int lg = lane >> 4;
    const int li = lane & 15;
    const float c1 = 0.18033688011112042f;   // 0.125 * log2(e)

    const int q = qBase + w * 16 + li;        // this lane's q row

    // Q fragments (B-operand): Q[q][dk = lg*8 + ks*32 + j]
    short8 qf[2];
#pragma unroll
    for (int ks = 0; ks < 2; ks++)
        qf[ks] = *(const short8*)&Qp[(size_t)(b * S_ + q) * D_ + h * 64 + lg * 8 + ks * 32];

    // staging addresses: thread covers 2 (row,slot) positions for K and V tiles
    const int r0 = tid >> 3, s0 = tid & 7, gs0 = s0 ^ (r0 & 7);
    const int r1 = (256 + tid) >> 3, s1 = tid & 7, gs1 = s1 ^ (r1 & 7);
    const short* kg0 = &Kp[(size_t)(b * S_ + r0) * D_ + h * 64 + gs0 * 8];
    const short* kg1 = &Kp[(size_t)(b * S_ + r1) * D_ + h * 64 + gs1 * 8];
    const short* vg0 = &Vt[(size_t)(bh * 64 + r0) * S_ + gs0 * 8];
    const short* vg1 = &Vt[(size_t)(bh * 64 + r1) * S_ + gs1 * 8];
    const uint32_t* mrow = &mp[(size_t)(b * S_ + q) * 64];

    // prologue: stage tile 0
    short8 stK0 = *(const short8*)kg0;
    short8 stK1 = *(const short8*)kg1;
    short8 stV0 = *(const short8*)vg0;
    short8 stV1 = *(const short8*)vg1;
    *(short8*)&Ks[0][r0 * 64 + s0 * 8] = stK0;
    *(short8*)&Ks[0][r1 * 64 + s1 * 8] = stK1;
    *(short8*)&Vs[0][r0 * 64 + s0 * 8] = stV0;
    *(short8*)&Vs[0][r1 * 64 + s1 * 8] = stV1;
    __syncthreads();
    uint2 mw = *(const uint2*)&mrow[0];

    float m_r = -1e30f, l_r = 0.f;
    f32x4 acc[4];
#pragma unroll
    for (int g = 0; g < 4; g++) acc[g] = (f32x4)0.f;

    short* psw = &Ps[w * 1024];
    int cur = 0;

    for (int kt = 0; kt < S_ / 64; ++kt) {
        uint2 mwn;
        if (kt < S_ / 64 - 1) {   // T14: issue next tile global->reg early
            size_t ko = (size_t)(kt + 1) * 64 * D_;
            int vo = (kt + 1) * 64;
            stK0 = *(const short8*)(kg0 + ko);
            stK1 = *(const short8*)(kg1 + ko);
            stV0 = *(const short8*)(vg0 + vo);
            stV1 = *(const short8*)(vg1 + vo);
            mwn = *(const uint2*)&mrow[(kt + 1) * 2];
        }

        // S^T = K Q^T (raw scores): lane holds S[k = nt*16 + lg*4 + r][q = li]
        f32x4 sc[4];
#pragma unroll
        for (int nt = 0; nt < 4; nt++) {
            f32x4 c = (f32x4)0.f;
#pragma unroll
            for (int ks = 0; ks < 2; ks++) {
                short8 kf = *(const short8*)&Ks[cur][(nt * 16 + li) * 64 + (((lg + ks * 4) ^ (li & 7)) << 3)];
                c = __builtin_amdgcn_mfma_f32_16x16x32_bf16(kf, qf[ks], c, 0, 0, 0);
            }
            sc[nt] = c;
        }

        // mask nibbles for this lane's 16 scores
        uint32_t nib[4];
#pragma unroll
        for (int nt = 0; nt < 4; nt++) {
            uint32_t wd = (nt < 2) ? mw.x : mw.y;
            nib[nt] = (wd >> (((nt & 1) << 4) + (lg << 2))) & 0xFu;
        }

        // in-register row max (raw units), cross-lg reduce
        float tm = fmaxf(fmaxf(fmaxf(sc[0][0], sc[0][1]), fmaxf(sc[0][2], sc[0][3])),
                         fmaxf(fmaxf(sc[1][0], sc[1][1]), fmaxf(sc[1][2], sc[1][3])));
        tm = fmaxf(tm, fmaxf(fmaxf(fmaxf(sc[2][0], sc[2][1]), fmaxf(sc[2][2], sc[2][3])),
                             fmaxf(fmaxf(sc[3][0], sc[3][1]), fmaxf(sc[3][2], sc[3][3]))));
        tm = fmaxf(tm, __shfl_xor(tm, 16));
        tm = fmaxf(tm, __shfl_xor(tm, 32));
        float mn = fmaxf(m_r, tm);
        float alpha = fexp2((m_r - mn) * c1);
        m_r = mn;
        float mc = mn * c1;

        // p = exp2(s*c1 - mc), masked; pack to bf16 pairs; accumulate sum
        float ls = 0.f;
#pragma unroll
        for (int nt = 0; nt < 4; nt++) {
            float e0 = fexp2(__builtin_fmaf(sc[nt][0], c1, -mc));
            float e1 = fexp2(__builtin_fmaf(sc[nt][1], c1, -mc));
            float e2 = fexp2(__builtin_fmaf(sc[nt][2], c1, -mc));
            float e3 = fexp2(__builtin_fmaf(sc[nt][3], c1, -mc));
            uint32_t nb = nib[nt];
            if (!(nb & 1u)) e0 = 0.f;
            if (!(nb & 2u)) e1 = 0.f;
            if (!(nb & 4u)) e2 = 0.f;
            if (!(nb & 8u)) e3 = 0.f;
            ls += (e0 + e1) + (e2 + e3);
            uint32_t p0 = cvt_pk_bf16(e0, e1);
            uint32_t p1 = cvt_pk_bf16(e2, e3);
            // P^T[k][q=li]: row li, 16B slot (2nt + (lg>>1)) ^ (li&7), 8B half lg&1
            *(uint2*)&psw[li * 64 + (((2 * nt + (lg >> 1)) ^ (li & 7)) << 3) + ((lg & 1) << 2)] =
                make_uint2(p0, p1);
        }
        ls += __shfl_xor(ls, 16);
        ls += __shfl_xor(ls, 32);
        l_r = l_r * alpha + ls;

        // rescale O accumulators
#pragma unroll
        for (int g = 0; g < 4; g++) acc[g] *= alpha;

        // O^T += V^T P^T : A = V^T frag, B = P^T frag
#pragma unroll
        for (int ks = 0; ks < 2; ks++) {
            short8 pb = *(const short8*)&psw[li * 64 + (((4 * ks + lg) ^ (li & 7)) << 3)];
#pragma unroll
            for (int g = 0; g < 4; g++) {
                short8 vf = *(const short8*)&Vs[cur][(g * 16 + li) * 64 + (((lg + ks * 4) ^ (li & 7)) << 3)];
                acc[g] = __builtin_amdgcn_mfma_f32_16x16x32_bf16(vf, pb, acc[g], 0, 0, 0);
            }
        }

        if (kt < S_ / 64 - 1) {
            *(short8*)&Ks[cur ^ 1][r0 * 64 + s0 * 8] = stK0;
            *(short8*)&Ks[cur ^ 1][r1 * 64 + s1 * 8] = stK1;
            *(short8*)&Vs[cur ^ 1][r0 * 64 + s0 * 8] = stV0;
            *(short8*)&Vs[cur ^ 1][r1 * 64 + s1 * 8] = stV1;
            __syncthreads();
            cur ^= 1;
            mw = mwn;
        }
    }

    // epilogue: O[q][dv] = acc[g][r] / l, dv = 16g + 4lg + r  -> packed 8B stores
    float inv = 1.f / l_r;
    short* orow = &Op[(size_t)(b * S_ + q) * D_ + h * 64];
#pragma unroll
    for (int g = 0; g < 4; g++) {
        uint2 o;
        o.x = cvt_pk_bf16(acc[g][0] * inv, acc[g][1] * inv);
        o.y = cvt_pk_bf16(acc[g][2] * inv, acc[g][3] * inv);
        *(uint2*)&orow[g * 16 + lg * 4] = o;
    }
}

extern "C" void kernel_launch(void* const* d_in, const int* in_sizes, int n_in,
                              void* d_out, int out_size, void* d_ws, size_t ws_size,
                              hipStream_t stream) {
    const float* q  = (const float*)d_in[0];
    const float* k  = (const float*)d_in[1];
    const float* v  = (const float*)d_in[2];
    const int*   mk = (const int*)d_in[3];
    const float* wq = (const float*)d_in[4];
    const float* wk = (const float*)d_in[5];
    const float* wv = (const float*)d_in[6];
    const float* wo = (const float*)d_in[7];

    const size_t SZ = (size_t)B_ * S_ * D_;
    const size_t DD = (size_t)D_ * D_;
    const size_t NEED = (6 * SZ + 4 * DD) * 2 + (size_t)B_ * S_ * 64 * 4;
    if (ws_size < NEED) return;

    short* ws  = (short*)d_ws;
    short* qb  = ws;
    short* kb  = qb + SZ;
    short* vb  = kb + SZ;
    short* wqb = vb + SZ;
    short* wkb = wqb + DD;
    short* wvb = wkb + DD;
    short* wob = wvb + DD;
    short* Qp  = wob + DD;
    short* Kp  = Qp + SZ;
    short* Vp  = Kp + SZ;
    uint32_t* mp = (uint32_t*)(Vp + SZ);
    short* Vtr = qb;            // alias: qb dead after Q-GEMM
    short* Opx = kb;            // alias: kb dead after K-GEMM

    dim3 blk(256);
    cast_qkv<<<dim3(3 * 2048), blk, 0, stream>>>(q, k, v, qb, kb, vb);
    cast_w4<<<dim3(4 * 512), blk, 0, stream>>>(wq, wk, wv, wo, wqb, wkb, wvb, wob);
    pack_mask<<<dim3((unsigned)((size_t)B_ * S_ * S_ / 256)), blk, 0, stream>>>(mk, mp);

    gemm_nt<0><<<dim3(D_ / 128, B_ * S_ / 128), blk, 0, stream>>>(qb, wqb, Qp, B_ * S_, D_, D_);
    gemm_nt<0><<<dim3(D_ / 128, B_ * S_ / 128), blk, 0, stream>>>(kb, wkb, Kp, B_ * S_, D_, D_);
    gemm_nt<0><<<dim3(D_ / 128, B_ * S_ / 128), blk, 0, stream>>>(vb, wvb, Vp, B_ * S_, D_, D_);

    transpose_v<<<dim3(B_ * H_ * (S_ / 64)), blk, 0, stream>>>(Vp, Vtr);

    attn_kernel<<<dim3(S_ / 64, B_ * H_), blk, 0, stream>>>(Qp, Kp, Vtr, mp, Opx);

    gemm_nt<1><<<dim3(D_ / 128, B_ * S_ / 128), blk, 0, stream>>>(Opx, wob, d_out, B_ * S_, D_, D_);
}

// Round 3
// 174.176 us; speedup vs baseline: 1.5390x; 1.2822x over previous
//
#include <hip/hip_runtime.h>
#include <stdint.h>

#define B_ 2
#define S_ 2048
#define D_ 1024
#define H_ 16
#define DK_ 64

typedef __attribute__((ext_vector_type(8))) short short8;   // 8 x bf16 (raw bits)
typedef __attribute__((ext_vector_type(4))) float f32x4;

__device__ __forceinline__ short f2bf(float f) {
    uint32_t u = __float_as_uint(f);
    return (short)((u + 0x7FFFu + ((u >> 16) & 1u)) >> 16);
}

__device__ __forceinline__ float fexp2(float x) {
    float r;
    asm("v_exp_f32 %0, %1" : "=v"(r) : "v"(x));
    return r;
}

__device__ __forceinline__ uint32_t cvt_pk_bf16(float lo, float hi) {
    uint32_t r;
    asm("v_cvt_pk_bf16_f32 %0, %1, %2" : "=v"(r) : "v"(lo), "v"(hi));
    return r;
}

#define GLOAD16(gptr, lptr)                                                      \
    __builtin_amdgcn_global_load_lds(                                            \
        (const __attribute__((address_space(1))) void*)(gptr),                   \
        (__attribute__((address_space(3))) void*)(lptr), 16, 0, 0)

// ---------------- cast f32 -> bf16: q,k,v merged ----------------
__global__ __launch_bounds__(256) void cast_qkv(const float* __restrict__ a,
                                                const float* __restrict__ b,
                                                const float* __restrict__ c,
                                                short* __restrict__ oa,
                                                short* __restrict__ ob,
                                                short* __restrict__ oc) {
    int bid = blockIdx.x;
    int sel = bid >> 11;
    int i = (bid & 2047) * 256 + threadIdx.x;
    const float* in = (sel == 0) ? a : (sel == 1) ? b : c;
    short* out = (sel == 0) ? oa : (sel == 1) ? ob : oc;
    const float4* p = ((const float4*)in) + (size_t)i * 2;
    float4 x = p[0], y = p[1];
    short8 o;
    o[0] = f2bf(x.x); o[1] = f2bf(x.y); o[2] = f2bf(x.z); o[3] = f2bf(x.w);
    o[4] = f2bf(y.x); o[5] = f2bf(y.y); o[6] = f2bf(y.z); o[7] = f2bf(y.w);
    *(((short8*)out) + i) = o;
}

// ---------------- cast f32 -> bf16: 4 weights merged ----------------
__global__ __launch_bounds__(256) void cast_w4(const float* __restrict__ a,
                                               const float* __restrict__ b,
                                               const float* __restrict__ c,
                                               const float* __restrict__ d,
                                               short* __restrict__ oa,
                                               short* __restrict__ ob,
                                               short* __restrict__ oc,
                                               short* __restrict__ od) {
    int bid = blockIdx.x;
    int sel = bid >> 9;
    int i = (bid & 511) * 256 + threadIdx.x;
    const float* in = (sel == 0) ? a : (sel == 1) ? b : (sel == 2) ? c : d;
    short* out = (sel == 0) ? oa : (sel == 1) ? ob : (sel == 2) ? oc : od;
    const float4* p = ((const float4*)in) + (size_t)i * 2;
    float4 x = p[0], y = p[1];
    short8 o;
    o[0] = f2bf(x.x); o[1] = f2bf(x.y); o[2] = f2bf(x.z); o[3] = f2bf(x.w);
    o[4] = f2bf(y.x); o[5] = f2bf(y.y); o[6] = f2bf(y.z); o[7] = f2bf(y.w);
    *(((short8*)out) + i) = o;
}

// ---------------- mask int32 -> bit-packed (4 elems/thread) + LUT init ----------------
__global__ __launch_bounds__(256) void pack_mask(const int* __restrict__ mask,
                                                 uint32_t* __restrict__ packed,
                                                 float* __restrict__ lut) {
    if (blockIdx.x == 0 && threadIdx.x < 64) {
        int e = threadIdx.x >> 2, r = threadIdx.x & 3;
        lut[threadIdx.x] = __int_as_float(((e >> r) & 1) ? 0x7F800000u : 0xFF800000u);
    }
    size_t t = (size_t)blockIdx.x * 256 + threadIdx.x;   // covers 4 elems
    int4 m = ((const int4*)mask)[t];
    uint32_t nib = (m.x != 0 ? 1u : 0u) | (m.y != 0 ? 2u : 0u) |
                   (m.z != 0 ? 4u : 0u) | (m.w != 0 ? 8u : 0u);
    int lane = threadIdx.x & 63;
    uint32_t v = nib << ((lane & 7) * 4);
    v |= __shfl_xor(v, 1);
    v |= __shfl_xor(v, 2);
    v |= __shfl_xor(v, 4);
    if ((lane & 7) == 0) packed[t >> 3] = v;
}

// ---------------- GEMM body macro: C[M,N] = A * W^T, 128x128 tile, BK=32 ----------------
#define GEMM_BODY(A, W, C, F32OUT, Mv, Nv, Kv)                                              \
    __shared__ short As[128 * 32];                                                          \
    __shared__ short Bs[128 * 32];                                                          \
    const int tid = threadIdx.x;                                                            \
    const int lane = tid & 63;                                                              \
    const int w = tid >> 6;                                                                 \
    const int wm = w >> 1, wn = w & 1;                                                      \
    const int mBase = blockIdx.y * 128, nBase = blockIdx.x * 128;                           \
    f32x4 acc[4][4];                                                                        \
    _Pragma("unroll") for (int i = 0; i < 4; i++)                                           \
        _Pragma("unroll") for (int j = 0; j < 4; j++) acc[i][j] = (f32x4)0.f;               \
    const int srow = lane >> 2;                                                             \
    const int sslot = lane & 3;                                                             \
    for (int k0 = 0; k0 < Kv; k0 += 32) {                                                   \
        _Pragma("unroll") for (int i = 0; i < 2; ++i) {                                     \
            int seg = w * 2 + i;                                                            \
            int row = seg * 16 + srow;                                                      \
            const short* ga = A + (size_t)(mBase + row) * Kv + k0 + sslot * 8;              \
            GLOAD16(ga, (char*)As + seg * 1024);                                            \
            const short* gb = W + (size_t)(nBase + row) * Kv + k0 + sslot * 8;              \
            GLOAD16(gb, (char*)Bs + seg * 1024);                                            \
        }                                                                                   \
        asm volatile("s_waitcnt vmcnt(0)" ::: "memory");                                    \
        __syncthreads();                                                                    \
        short8 af[4], bfv[4];                                                               \
        _Pragma("unroll") for (int mi = 0; mi < 4; mi++)                                    \
            af[mi] = *(const short8*)&As[(wm * 64 + mi * 16 + (lane & 15)) * 32 + (lane >> 4) * 8]; \
        _Pragma("unroll") for (int ni = 0; ni < 4; ni++)                                    \
            bfv[ni] = *(const short8*)&Bs[(wn * 64 + ni * 16 + (lane & 15)) * 32 + (lane >> 4) * 8]; \
        _Pragma("unroll") for (int mi = 0; mi < 4; mi++)                                    \
            _Pragma("unroll") for (int ni = 0; ni < 4; ni++)                                \
                acc[mi][ni] = __builtin_amdgcn_mfma_f32_16x16x32_bf16(af[mi], bfv[ni], acc[mi][ni], 0, 0, 0); \
        __syncthreads();                                                                    \
    }                                                                                       \
    _Pragma("unroll") for (int mi = 0; mi < 4; mi++)                                        \
        _Pragma("unroll") for (int ni = 0; ni < 4; ni++)                                    \
            _Pragma("unroll") for (int r = 0; r < 4; r++) {                                 \
                int row = mBase + wm * 64 + mi * 16 + (lane >> 4) * 4 + r;                  \
                int col = nBase + wn * 64 + ni * 16 + (lane & 15);                          \
                float v = acc[mi][ni][r];                                                   \
                if (F32OUT) ((float*)C)[(size_t)row * Nv + col] = v;                        \
                else        ((short*)C)[(size_t)row * Nv + col] = f2bf(v);                  \
            }

// batched Q/K/V projection (blockIdx.z selects)
__global__ __launch_bounds__(256) void gemm3_nt(const short* __restrict__ A0, const short* __restrict__ W0, short* __restrict__ C0,
                                                const short* __restrict__ A1, const short* __restrict__ W1, short* __restrict__ C1,
                                                const short* __restrict__ A2, const short* __restrict__ W2, short* __restrict__ C2) {
    const int z = blockIdx.z;
    const short* A = (z == 0) ? A0 : (z == 1) ? A1 : A2;
    const short* W = (z == 0) ? W0 : (z == 1) ? W1 : W2;
    short* C = (z == 0) ? C0 : (z == 1) ? C1 : C2;
    GEMM_BODY(A, W, C, 0, (B_ * S_), D_, D_)
}

__global__ __launch_bounds__(256) void gemm_out(const short* __restrict__ A,
                                                const short* __restrict__ W,
                                                float* __restrict__ C) {
    GEMM_BODY(A, W, C, 1, (B_ * S_), D_, D_)
}

// ---------------- V transpose ----------------
__global__ __launch_bounds__(256) void transpose_v(const short* __restrict__ Vp,
                                                   short* __restrict__ Vt) {
    __shared__ short t[64 * 72];
    int bid = blockIdx.x;
    int bh = bid >> 5;
    int st = bid & 31;
    int b = bh >> 4, h = bh & 15;
    int sBase = st * 64;
    int tid = threadIdx.x;
#pragma unroll
    for (int i = 0; i < 2; i++) {
        int ci = i * 256 + tid;
        int sr = ci >> 3, sl = ci & 7;
        short8 v = *(const short8*)&Vp[(size_t)(b * S_ + sBase + sr) * D_ + h * 64 + sl * 8];
#pragma unroll
        for (int j = 0; j < 8; j++) t[(sl * 8 + j) * 72 + sr] = v[j];
    }
    __syncthreads();
#pragma unroll
    for (int i = 0; i < 2; i++) {
        int ci = i * 256 + tid;
        int dk = ci >> 3, sl = ci & 7;
        short8 o = *(const short8*)&t[dk * 72 + sl * 8];
        *(short8*)&Vt[(size_t)((b * H_ + h) * 64 + dk) * S_ + sBase + sl * 8] = o;
    }
}

// ---------------- flash attention ----------------
// grid (S/64, B*H), 4 waves; wave w owns q rows [qBase+w*16,+16); lane li owns q row li.
__global__ __launch_bounds__(256) void attn_kernel(const short* __restrict__ Qp,
                                                   const short* __restrict__ Kp,
                                                   const short* __restrict__ Vt,
                                                   const uint32_t* __restrict__ mp,
                                                   const float* __restrict__ lutg,
                                                   short* __restrict__ Op) {
    __shared__ short Ks[2][64 * 64];
    __shared__ short Vs[2][64 * 64];
    __shared__ short Ps[4 * 16 * 64];
    const int qt = blockIdx.x;
    const int bh = blockIdx.y;
    const int b = bh >> 4, h = bh & 15;
    const int qBase = qt * 64;
    const int tid = threadIdx.x, lane = tid & 63, w = tid >> 6;
    const int lg = lane >> 4;
    const int li = lane & 15;
    const float c1 = 0.18033688011112042f;   // 0.125 * log2(e)

    const int q = qBase + w * 16 + li;

    short8 qf[2];
#pragma unroll
    for (int ks = 0; ks < 2; ks++)
        qf[ks] = *(const short8*)&Qp[(size_t)(b * S_ + q) * D_ + h * 64 + lg * 8 + ks * 32];

    // staging source pointers: line0 rows 0-31, line1 rows 32-63; dest = linear tid*16
    const int r0 = tid >> 3, sl = tid & 7;
    const int gs = sl ^ (r0 & 7);            // (r0+32)&7 == r0&7
    const short* kg0 = Kp + ((size_t)(b * S_) + r0) * D_ + h * 64 + gs * 8;
    const short* kg1 = kg0 + (size_t)32 * D_;
    const short* vg0 = Vt + ((size_t)bh * 64 + r0) * S_ + gs * 8;
    const short* vg1 = vg0 + (size_t)32 * S_;
    const uint32_t* mrow = mp + ((size_t)(b * S_) + q) * 64;
    char* ldsK = (char*)&Ks[0][0];
    char* ldsV = (char*)&Vs[0][0];
    const int woff = w * 1024;

    // prologue: stage tile 0 into buffer 0
    GLOAD16(kg0, ldsK + woff);
    GLOAD16(kg1, ldsK + 4096 + woff);
    GLOAD16(vg0, ldsV + woff);
    GLOAD16(vg1, ldsV + 4096 + woff);
    uint2 mw = *(const uint2*)mrow;
    asm volatile("s_waitcnt vmcnt(0)" ::: "memory");
    __syncthreads();

    float m_r = -1e30f, l_r = 0.f;
    f32x4 acc[4];
#pragma unroll
    for (int g = 0; g < 4; g++) acc[g] = (f32x4)0.f;

    short* psw = &Ps[w * 1024];
    int cur = 0;

    for (int kt = 0; kt < S_ / 64; ++kt) {
        // mask nibbles + issue LUT loads early (latency hides under MFMA)
        f32x4 msk[4];
#pragma unroll
        for (int nt = 0; nt < 4; nt++) {
            uint32_t wd = (nt < 2) ? mw.x : mw.y;
            uint32_t nib = (wd >> (((nt & 1) << 4) + (lg << 2))) & 0xFu;
            msk[nt] = *(const f32x4*)&lutg[nib * 4];
        }

        uint2 mwn;
        if (kt < S_ / 64 - 1) {   // async prefetch of next K/V tile into buf cur^1
            const size_t ko = (size_t)((kt + 1) * 64) * D_;
            const int vo = (kt + 1) * 64;
            const int boff = (cur ^ 1) * 8192 + woff;
            GLOAD16(kg0 + ko, ldsK + boff);
            GLOAD16(kg1 + ko, ldsK + boff + 4096);
            GLOAD16(vg0 + vo, ldsV + boff);
            GLOAD16(vg1 + vo, ldsV + boff + 4096);
            mwn = *(const uint2*)&mrow[(kt + 1) * 2];
        }

        // S^T = K Q^T: lane holds S[k = nt*16 + lg*4 + r][q = li] (raw scores)
        f32x4 sc[4];
        __builtin_amdgcn_s_setprio(1);
#pragma unroll
        for (int nt = 0; nt < 4; nt++) {
            f32x4 c = (f32x4)0.f;
#pragma unroll
            for (int ks = 0; ks < 2; ks++) {
                short8 kf = *(const short8*)&Ks[cur][(nt * 16 + li) * 64 + (((lg + ks * 4) ^ (li & 7)) << 3)];
                c = __builtin_amdgcn_mfma_f32_16x16x32_bf16(kf, qf[ks], c, 0, 0, 0);
            }
            sc[nt] = c;
        }
        __builtin_amdgcn_s_setprio(0);

        // row max (raw units, unmasked is OK) + cross-half reduce
        float tm = fmaxf(fmaxf(fmaxf(sc[0][0], sc[0][1]), fmaxf(sc[0][2], sc[0][3])),
                         fmaxf(fmaxf(sc[1][0], sc[1][1]), fmaxf(sc[1][2], sc[1][3])));
        tm = fmaxf(tm, fmaxf(fmaxf(fmaxf(sc[2][0], sc[2][1]), fmaxf(sc[2][2], sc[2][3])),
                             fmaxf(fmaxf(sc[3][0], sc[3][1]), fmaxf(sc[3][2], sc[3][3]))));
        tm = fmaxf(tm, __shfl_xor(tm, 16));
        tm = fmaxf(tm, __shfl_xor(tm, 32));

        // T13 defer-max: rescale only when max grew materially (p bounded by 2^10)
        if (__any((tm - m_r) * c1 > 10.0f)) {
            float mn = fmaxf(m_r, tm);
            float alpha = fexp2((m_r - mn) * c1);
            m_r = mn;
            l_r *= alpha;
#pragma unroll
            for (int g = 0; g < 4; g++) acc[g] *= alpha;
        }
        float mc = m_r * c1;

        // p = exp2(min(s*c1 - mc, ±inf_mask)); pack bf16; sum
        float ls = 0.f;
#pragma unroll
        for (int nt = 0; nt < 4; nt++) {
            float e0 = fexp2(fminf(__builtin_fmaf(sc[nt][0], c1, -mc), msk[nt][0]));
            float e1 = fexp2(fminf(__builtin_fmaf(sc[nt][1], c1, -mc), msk[nt][1]));
            float e2 = fexp2(fminf(__builtin_fmaf(sc[nt][2], c1, -mc), msk[nt][2]));
            float e3 = fexp2(fminf(__builtin_fmaf(sc[nt][3], c1, -mc), msk[nt][3]));
            ls += (e0 + e1) + (e2 + e3);
            uint32_t p0 = cvt_pk_bf16(e0, e1);
            uint32_t p1 = cvt_pk_bf16(e2, e3);
            *(uint2*)&psw[li * 64 + (((2 * nt + (lg >> 1)) ^ (li & 7)) << 3) + ((lg & 1) << 2)] =
                make_uint2(p0, p1);
        }
        ls += __shfl_xor(ls, 16);
        ls += __shfl_xor(ls, 32);
        l_r += ls;

        // O^T += V^T P^T
        __builtin_amdgcn_s_setprio(1);
#pragma unroll
        for (int ks = 0; ks < 2; ks++) {
            short8 pb = *(const short8*)&psw[li * 64 + (((4 * ks + lg) ^ (li & 7)) << 3)];
#pragma unroll
            for (int g = 0; g < 4; g++) {
                short8 vf = *(const short8*)&Vs[cur][(g * 16 + li) * 64 + (((lg + ks * 4) ^ (li & 7)) << 3)];
                acc[g] = __builtin_amdgcn_mfma_f32_16x16x32_bf16(vf, pb, acc[g], 0, 0, 0);
            }
        }
        __builtin_amdgcn_s_setprio(0);

        asm volatile("s_waitcnt vmcnt(0)" ::: "memory");   // prefetch landed
        __syncthreads();
        cur ^= 1;
        if (kt < S_ / 64 - 1) mw = mwn;
    }

    // epilogue
    float inv = 1.f / l_r;
    short* orow = &Op[(size_t)(b * S_ + q) * D_ + h * 64];
#pragma unroll
    for (int g = 0; g < 4; g++) {
        uint2 o;
        o.x = cvt_pk_bf16(acc[g][0] * inv, acc[g][1] * inv);
        o.y = cvt_pk_bf16(acc[g][2] * inv, acc[g][3] * inv);
        *(uint2*)&orow[g * 16 + lg * 4] = o;
    }
}

extern "C" void kernel_launch(void* const* d_in, const int* in_sizes, int n_in,
                              void* d_out, int out_size, void* d_ws, size_t ws_size,
                              hipStream_t stream) {
    const float* q  = (const float*)d_in[0];
    const float* k  = (const float*)d_in[1];
    const float* v  = (const float*)d_in[2];
    const int*   mk = (const int*)d_in[3];
    const float* wq = (const float*)d_in[4];
    const float* wk = (const float*)d_in[5];
    const float* wv = (const float*)d_in[6];
    const float* wo = (const float*)d_in[7];

    const size_t SZ = (size_t)B_ * S_ * D_;
    const size_t DD = (size_t)D_ * D_;
    const size_t NEED = (6 * SZ + 4 * DD) * 2 + (size_t)B_ * S_ * 64 * 4 + 256;
    if (ws_size < NEED) return;

    short* ws  = (short*)d_ws;
    short* qb  = ws;
    short* kb  = qb + SZ;
    short* vb  = kb + SZ;
    short* wqb = vb + SZ;
    short* wkb = wqb + DD;
    short* wvb = wkb + DD;
    short* wob = wvb + DD;
    short* Qp  = wob + DD;
    short* Kp  = Qp + SZ;
    short* Vp  = Kp + SZ;
    uint32_t* mp = (uint32_t*)(Vp + SZ);
    float* lutg = (float*)(mp + (size_t)B_ * S_ * 64);
    short* Vtr = qb;            // alias: qb dead after Q-GEMM
    short* Opx = kb;            // alias: kb dead after K-GEMM

    dim3 blk(256);
    cast_qkv<<<dim3(3 * 2048), blk, 0, stream>>>(q, k, v, qb, kb, vb);
    cast_w4<<<dim3(4 * 512), blk, 0, stream>>>(wq, wk, wv, wo, wqb, wkb, wvb, wob);
    pack_mask<<<dim3((unsigned)((size_t)B_ * S_ * S_ / 4 / 256)), blk, 0, stream>>>(mk, mp, lutg);

    gemm3_nt<<<dim3(D_ / 128, B_ * S_ / 128, 3), blk, 0, stream>>>(
        qb, wqb, Qp, kb, wkb, Kp, vb, wvb, Vp);

    transpose_v<<<dim3(B_ * H_ * (S_ / 64)), blk, 0, stream>>>(Vp, Vtr);

    attn_kernel<<<dim3(S_ / 64, B_ * H_), blk, 0, stream>>>(Qp, Kp, Vtr, mp, lutg, Opx);

    gemm_out<<<dim3(D_ / 128, B_ * S_ / 128), blk, 0, stream>>>(Opx, wob, (float*)d_out);
}

// Round 5
// 171.680 us; speedup vs baseline: 1.5613x; 1.0145x over previous
//
#include <hip/hip_runtime.h>
#include <stdint.h>

#define B_ 2
#define S_ 2048
#define D_ 1024
#define H_ 16
#define DK_ 64

typedef __attribute__((ext_vector_type(8))) short short8;   // 8 x bf16 (raw bits)
typedef __attribute__((ext_vector_type(4))) float f32x4;

__device__ __forceinline__ short f2bf(float f) {
    uint32_t u = __float_as_uint(f);
    return (short)((u + 0x7FFFu + ((u >> 16) & 1u)) >> 16);
}

__device__ __forceinline__ float fexp2(float x) {
    float r;
    asm("v_exp_f32 %0, %1" : "=v"(r) : "v"(x));
    return r;
}

__device__ __forceinline__ uint32_t cvt_pk_bf16(float lo, float hi) {
    uint32_t r;
    asm("v_cvt_pk_bf16_f32 %0, %1, %2" : "=v"(r) : "v"(lo), "v"(hi));
    return r;
}

#define GLOAD16(gptr, lptr)                                                      \
    __builtin_amdgcn_global_load_lds(                                            \
        (const __attribute__((address_space(1))) void*)(gptr),                   \
        (__attribute__((address_space(3))) void*)(lptr), 16, 0, 0)

// ---------------- cast f32 -> bf16: q,k,v merged ----------------
__global__ __launch_bounds__(256) void cast_qkv(const float* __restrict__ a,
                                                const float* __restrict__ b,
                                                const float* __restrict__ c,
                                                short* __restrict__ oa,
                                                short* __restrict__ ob,
                                                short* __restrict__ oc) {
    int bid = blockIdx.x;
    int sel = bid >> 11;
    int i = (bid & 2047) * 256 + threadIdx.x;
    const float* in = (sel == 0) ? a : (sel == 1) ? b : c;
    short* out = (sel == 0) ? oa : (sel == 1) ? ob : oc;
    const float4* p = ((const float4*)in) + (size_t)i * 2;
    float4 x = p[0], y = p[1];
    short8 o;
    o[0] = f2bf(x.x); o[1] = f2bf(x.y); o[2] = f2bf(x.z); o[3] = f2bf(x.w);
    o[4] = f2bf(y.x); o[5] = f2bf(y.y); o[6] = f2bf(y.z); o[7] = f2bf(y.w);
    *(((short8*)out) + i) = o;
}

// ---------------- cast f32 -> bf16: 4 weights merged ----------------
__global__ __launch_bounds__(256) void cast_w4(const float* __restrict__ a,
                                               const float* __restrict__ b,
                                               const float* __restrict__ c,
                                               const float* __restrict__ d,
                                               short* __restrict__ oa,
                                               short* __restrict__ ob,
                                               short* __restrict__ oc,
                                               short* __restrict__ od) {
    int bid = blockIdx.x;
    int sel = bid >> 9;
    int i = (bid & 511) * 256 + threadIdx.x;
    const float* in = (sel == 0) ? a : (sel == 1) ? b : (sel == 2) ? c : d;
    short* out = (sel == 0) ? oa : (sel == 1) ? ob : (sel == 2) ? oc : od;
    const float4* p = ((const float4*)in) + (size_t)i * 2;
    float4 x = p[0], y = p[1];
    short8 o;
    o[0] = f2bf(x.x); o[1] = f2bf(x.y); o[2] = f2bf(x.z); o[3] = f2bf(x.w);
    o[4] = f2bf(y.x); o[5] = f2bf(y.y); o[6] = f2bf(y.z); o[7] = f2bf(y.w);
    *(((short8*)out) + i) = o;
}

// ---------------- mask int32 -> bit-packed (4 elems/thread) + LUT init ----------------
__global__ __launch_bounds__(256) void pack_mask(const int* __restrict__ mask,
                                                 uint32_t* __restrict__ packed,
                                                 float* __restrict__ lut) {
    if (blockIdx.x == 0 && threadIdx.x < 64) {
        int e = threadIdx.x >> 2, r = threadIdx.x & 3;
        lut[threadIdx.x] = __int_as_float(((e >> r) & 1) ? 0x7F800000u : 0xFF800000u);
    }
    size_t t = (size_t)blockIdx.x * 256 + threadIdx.x;   // covers 4 elems
    int4 m = ((const int4*)mask)[t];
    uint32_t nib = (m.x != 0 ? 1u : 0u) | (m.y != 0 ? 2u : 0u) |
                   (m.z != 0 ? 4u : 0u) | (m.w != 0 ? 8u : 0u);
    int lane = threadIdx.x & 63;
    uint32_t v = nib << ((lane & 7) * 4);
    v |= __shfl_xor(v, 1);
    v |= __shfl_xor(v, 2);
    v |= __shfl_xor(v, 4);
    if ((lane & 7) == 0) packed[t >> 3] = v;
}

// ---------------- GEMM body: C[M,N] = A * W^T, 128x128 tile, BK=32 ----------------
// grid must be (8, 32[, z]); XCD-chunked swizzle: each XCD gets 4 M-rows x 8 N-cols.
#define GEMM_BODY(A, W, C, F32OUT, Mv, Nv, Kv)                                              \
    __shared__ short As[128 * 32];                                                          \
    __shared__ short Bs[128 * 32];                                                          \
    const int tid = threadIdx.x;                                                            \
    const int lane = tid & 63;                                                              \
    const int w = tid >> 6;                                                                 \
    const int wm = w >> 1, wn = w & 1;                                                      \
    const int l_ = blockIdx.x + (blockIdx.y << 3);                                          \
    const int xcd_ = l_ & 7, ii_ = l_ >> 3;                                                 \
    const int mBase = ((xcd_ << 2) + (ii_ >> 3)) * 128;                                     \
    const int nBase = (ii_ & 7) * 128;                                                      \
    f32x4 acc[4][4];                                                                        \
    _Pragma("unroll") for (int i = 0; i < 4; i++)                                           \
        _Pragma("unroll") for (int j = 0; j < 4; j++) acc[i][j] = (f32x4)0.f;               \
    const int srow = lane >> 2;                                                             \
    const int sslot = lane & 3;                                                             \
    for (int k0 = 0; k0 < Kv; k0 += 32) {                                                   \
        _Pragma("unroll") for (int i = 0; i < 2; ++i) {                                     \
            int seg = w * 2 + i;                                                            \
            int row = seg * 16 + srow;                                                      \
            const short* ga = A + (size_t)(mBase + row) * Kv + k0 + sslot * 8;              \
            GLOAD16(ga, (char*)As + seg * 1024);                                            \
            const short* gb = W + (size_t)(nBase + row) * Kv + k0 + sslot * 8;              \
            GLOAD16(gb, (char*)Bs + seg * 1024);                                            \
        }                                                                                   \
        asm volatile("s_waitcnt vmcnt(0)" ::: "memory");                                    \
        __syncthreads();                                                                    \
        short8 af[4], bfv[4];                                                               \
        _Pragma("unroll") for (int mi = 0; mi < 4; mi++)                                    \
            af[mi] = *(const short8*)&As[(wm * 64 + mi * 16 + (lane & 15)) * 32 + (lane >> 4) * 8]; \
        _Pragma("unroll") for (int ni = 0; ni < 4; ni++)                                    \
            bfv[ni] = *(const short8*)&Bs[(wn * 64 + ni * 16 + (lane & 15)) * 32 + (lane >> 4) * 8]; \
        _Pragma("unroll") for (int mi = 0; mi < 4; mi++)                                    \
            _Pragma("unroll") for (int ni = 0; ni < 4; ni++)                                \
                acc[mi][ni] = __builtin_amdgcn_mfma_f32_16x16x32_bf16(af[mi], bfv[ni], acc[mi][ni], 0, 0, 0); \
        __syncthreads();                                                                    \
    }                                                                                       \
    _Pragma("unroll") for (int mi = 0; mi < 4; mi++)                                        \
        _Pragma("unroll") for (int ni = 0; ni < 4; ni++)                                    \
            _Pragma("unroll") for (int r = 0; r < 4; r++) {                                 \
                int row = mBase + wm * 64 + mi * 16 + (lane >> 4) * 4 + r;                  \
                int col = nBase + wn * 64 + ni * 16 + (lane & 15);                          \
                float v = acc[mi][ni][r];                                                   \
                if (F32OUT) ((float*)C)[(size_t)row * Nv + col] = v;                        \
                else        ((short*)C)[(size_t)row * Nv + col] = f2bf(v);                  \
            }

__global__ __launch_bounds__(256) void gemm3_nt(const short* __restrict__ A0, const short* __restrict__ W0, short* __restrict__ C0,
                                                const short* __restrict__ A1, const short* __restrict__ W1, short* __restrict__ C1,
                                                const short* __restrict__ A2, const short* __restrict__ W2, short* __restrict__ C2) {
    const int z = blockIdx.z;
    const short* A = (z == 0) ? A0 : (z == 1) ? A1 : A2;
    const short* W = (z == 0) ? W0 : (z == 1) ? W1 : W2;
    short* C = (z == 0) ? C0 : (z == 1) ? C1 : C2;
    GEMM_BODY(A, W, C, 0, (B_ * S_), D_, D_)
}

__global__ __launch_bounds__(256) void gemm_out(const short* __restrict__ A,
                                                const short* __restrict__ W,
                                                float* __restrict__ C) {
    GEMM_BODY(A, W, C, 1, (B_ * S_), D_, D_)
}

// ---------------- V transpose ----------------
__global__ __launch_bounds__(256) void transpose_v(const short* __restrict__ Vp,
                                                   short* __restrict__ Vt) {
    __shared__ short t[64 * 72];
    int bid = blockIdx.x;
    int bh = bid >> 5;
    int st = bid & 31;
    int b = bh >> 4, h = bh & 15;
    int sBase = st * 64;
    int tid = threadIdx.x;
#pragma unroll
    for (int i = 0; i < 2; i++) {
        int ci = i * 256 + tid;
        int sr = ci >> 3, sl = ci & 7;
        short8 v = *(const short8*)&Vp[(size_t)(b * S_ + sBase + sr) * D_ + h * 64 + sl * 8];
#pragma unroll
        for (int j = 0; j < 8; j++) t[(sl * 8 + j) * 72 + sr] = v[j];
    }
    __syncthreads();
#pragma unroll
    for (int i = 0; i < 2; i++) {
        int ci = i * 256 + tid;
        int dk = ci >> 3, sl = ci & 7;
        short8 o = *(const short8*)&t[dk * 72 + sl * 8];
        *(short8*)&Vt[(size_t)((b * H_ + h) * 64 + dk) * S_ + sBase + sl * 8] = o;
    }
}

// ---------------- flash attention ----------------
// grid (32, 32) swizzled; 4 waves; wave w owns q rows [qBase+w*16,+16); lane li owns q row li.
__global__ __launch_bounds__(256) void attn_kernel(const short* __restrict__ Qp,
                                                   const short* __restrict__ Kp,
                                                   const short* __restrict__ Vt,
                                                   const uint32_t* __restrict__ mp,
                                                   const float* __restrict__ lutg,
                                                   short* __restrict__ Op) {
    __shared__ short Ks[2][64 * 64];
    __shared__ short Vs[2][64 * 64];
    // XCD-chunked: each XCD owns 4 consecutive bh (K/V L2-resident)
    const int l_ = blockIdx.x + (blockIdx.y << 5);
    const int bh = ((l_ & 7) << 2) + (l_ >> 8);
    const int qt = (l_ >> 3) & 31;
    const int b = bh >> 4, h = bh & 15;
    const int qBase = qt * 64;
    const int tid = threadIdx.x, lane = tid & 63, w = tid >> 6;
    const int lg = lane >> 4;
    const int li = lane & 15;
    const float c1 = 0.18033688011112042f;   // 0.125 * log2(e)

    const int q = qBase + w * 16 + li;

    short8 qf[2];
#pragma unroll
    for (int ks = 0; ks < 2; ks++)
        qf[ks] = *(const short8*)&Qp[(size_t)(b * S_ + q) * D_ + h * 64 + lg * 8 + ks * 32];

    // staging source pointers: dest = linear tid*16, source pre-swizzled
    const int r0 = tid >> 3, sl = tid & 7;
    const int gs = sl ^ (r0 & 7);
    const short* kg0 = Kp + ((size_t)(b * S_) + r0) * D_ + h * 64 + gs * 8;
    const short* kg1 = kg0 + (size_t)32 * D_;
    const short* vg0 = Vt + ((size_t)bh * 64 + r0) * S_ + gs * 8;
    const short* vg1 = vg0 + (size_t)32 * S_;
    const uint32_t* mrow = mp + ((size_t)(b * S_) + q) * 64;
    char* ldsK = (char*)&Ks[0][0];
    char* ldsV = (char*)&Vs[0][0];
    const int woff = w * 1024;

    // prologue: stage tile 0 into buffer 0
    GLOAD16(kg0, ldsK + woff);
    GLOAD16(kg1, ldsK + 4096 + woff);
    GLOAD16(vg0, ldsV + woff);
    GLOAD16(vg1, ldsV + 4096 + woff);
    uint2 mw = *(const uint2*)mrow;
    asm volatile("s_waitcnt vmcnt(0)" ::: "memory");
    __syncthreads();

    float m_r = -1e30f, l_r = 0.f;
    f32x4 acc[4];
#pragma unroll
    for (int g = 0; g < 4; g++) acc[g] = (f32x4)0.f;

    int cur = 0;

    for (int kt = 0; kt < S_ / 64; ++kt) {
        // mask LUT loads issued early
        f32x4 msk[4];
#pragma unroll
        for (int nt = 0; nt < 4; nt++) {
            uint32_t wd = (nt < 2) ? mw.x : mw.y;
            uint32_t nib = (wd >> (((nt & 1) << 4) + (lg << 2))) & 0xFu;
            msk[nt] = *(const f32x4*)&lutg[nib * 4];
        }

        uint2 mwn;
        if (kt < S_ / 64 - 1) {   // async prefetch of next K/V tile
            const size_t ko = (size_t)((kt + 1) * 64) * D_;
            const int vo = (kt + 1) * 64;
            const int boff = (cur ^ 1) * 8192 + woff;
            GLOAD16(kg0 + ko, ldsK + boff);
            GLOAD16(kg1 + ko, ldsK + boff + 4096);
            GLOAD16(vg0 + vo, ldsV + boff);
            GLOAD16(vg1 + vo, ldsV + boff + 4096);
            mwn = *(const uint2*)&mrow[(kt + 1) * 2];
        }

        // S^T = K Q^T: lane holds S[k = nt*16 + lg*4 + r][q = li] (raw scores)
        f32x4 sc[4];
        __builtin_amdgcn_s_setprio(1);
#pragma unroll
        for (int nt = 0; nt < 4; nt++) {
            f32x4 c = (f32x4)0.f;
#pragma unroll
            for (int ks = 0; ks < 2; ks++) {
                short8 kf = *(const short8*)&Ks[cur][(nt * 16 + li) * 64 + (((lg + ks * 4) ^ (li & 7)) << 3)];
                c = __builtin_amdgcn_mfma_f32_16x16x32_bf16(kf, qf[ks], c, 0, 0, 0);
            }
            sc[nt] = c;
        }
        __builtin_amdgcn_s_setprio(0);

        // row max (raw units) -- cross-group reduce via shfl (proven semantics)
        float tm = fmaxf(fmaxf(fmaxf(sc[0][0], sc[0][1]), fmaxf(sc[0][2], sc[0][3])),
                         fmaxf(fmaxf(sc[1][0], sc[1][1]), fmaxf(sc[1][2], sc[1][3])));
        tm = fmaxf(tm, fmaxf(fmaxf(fmaxf(sc[2][0], sc[2][1]), fmaxf(sc[2][2], sc[2][3])),
                             fmaxf(fmaxf(sc[3][0], sc[3][1]), fmaxf(sc[3][2], sc[3][3]))));
        tm = fmaxf(tm, __shfl_xor(tm, 16));
        tm = fmaxf(tm, __shfl_xor(tm, 32));

        // T13 defer-max
        if (__any((tm - m_r) * c1 > 10.0f)) {
            float mn = fmaxf(m_r, tm);
            float alpha = fexp2((m_r - mn) * c1);
            m_r = mn;
            l_r *= alpha;
#pragma unroll
            for (int g = 0; g < 4; g++) acc[g] *= alpha;
        }
        float mc = m_r * c1;

        // p = exp2(min(s*c1 - mc, +-inf)); pack bf16 pairs into u[nt][h]
        uint32_t u[4][2];
        float ls = 0.f;
#pragma unroll
        for (int nt = 0; nt < 4; nt++) {
            float e0 = fexp2(fminf(__builtin_fmaf(sc[nt][0], c1, -mc), msk[nt][0]));
            float e1 = fexp2(fminf(__builtin_fmaf(sc[nt][1], c1, -mc), msk[nt][1]));
            float e2 = fexp2(fminf(__builtin_fmaf(sc[nt][2], c1, -mc), msk[nt][2]));
            float e3 = fexp2(fminf(__builtin_fmaf(sc[nt][3], c1, -mc), msk[nt][3]));
            ls += (e0 + e1) + (e2 + e3);
            u[nt][0] = cvt_pk_bf16(e0, e1);
            u[nt][1] = cvt_pk_bf16(e2, e3);
        }
        ls += __shfl_xor(ls, 16);
        ls += __shfl_xor(ls, 32);
        l_r += ls;

        // O^T += V^T P^T with in-register P redistribution via shfl_xor(16):
        // group lg's B-frag holds k-chunk f = ks*4 + 2*(lg&1) + (lg>>1);
        // chunk data lives in nt = 2ks + (lg&1): low half in group (lg&~1), high in (lg|1).
        // Even groups export u[2ks+1][h] to their odd partner; odd export u[2ks][h].
        __builtin_amdgcn_s_setprio(1);
#pragma unroll
        for (int ks = 0; ks < 2; ks++) {
            const uint32_t s00 = u[2 * ks][0], s01 = u[2 * ks][1];
            const uint32_t s10 = u[2 * ks + 1][0], s11 = u[2 * ks + 1][1];
            uint32_t e0 = (lg & 1) ? s00 : s10;
            uint32_t e1 = (lg & 1) ? s01 : s11;
            uint32_t x0 = (uint32_t)__shfl_xor((int)e0, 16);
            uint32_t x1 = (uint32_t)__shfl_xor((int)e1, 16);
            union { uint32_t w4[4]; short8 s8; } pu;
            pu.w4[0] = (lg & 1) ? x0 : s00;
            pu.w4[1] = (lg & 1) ? x1 : s01;
            pu.w4[2] = (lg & 1) ? s10 : x0;
            pu.w4[3] = (lg & 1) ? s11 : x1;
            const int f = ks * 4 + ((lg & 1) << 1) + (lg >> 1);
#pragma unroll
            for (int g = 0; g < 4; g++) {
                short8 vf = *(const short8*)&Vs[cur][(g * 16 + li) * 64 + ((f ^ (li & 7)) << 3)];
                acc[g] = __builtin_amdgcn_mfma_f32_16x16x32_bf16(vf, pu.s8, acc[g], 0, 0, 0);
            }
        }
        __builtin_amdgcn_s_setprio(0);

        asm volatile("s_waitcnt vmcnt(0)" ::: "memory");   // prefetch landed
        __syncthreads();
        cur ^= 1;
        if (kt < S_ / 64 - 1) mw = mwn;
    }

    // epilogue
    float inv = 1.f / l_r;
    short* orow = &Op[(size_t)(b * S_ + q) * D_ + h * 64];
#pragma unroll
    for (int g = 0; g < 4; g++) {
        uint2 o;
        o.x = cvt_pk_bf16(acc[g][0] * inv, acc[g][1] * inv);
        o.y = cvt_pk_bf16(acc[g][2] * inv, acc[g][3] * inv);
        *(uint2*)&orow[g * 16 + lg * 4] = o;
    }
}

extern "C" void kernel_launch(void* const* d_in, const int* in_sizes, int n_in,
                              void* d_out, int out_size, void* d_ws, size_t ws_size,
                              hipStream_t stream) {
    const float* q  = (const float*)d_in[0];
    const float* k  = (const float*)d_in[1];
    const float* v  = (const float*)d_in[2];
    const int*   mk = (const int*)d_in[3];
    const float* wq = (const float*)d_in[4];
    const float* wk = (const float*)d_in[5];
    const float* wv = (const float*)d_in[6];
    const float* wo = (const float*)d_in[7];

    const size_t SZ = (size_t)B_ * S_ * D_;
    const size_t DD = (size_t)D_ * D_;
    const size_t NEED = (6 * SZ + 4 * DD) * 2 + (size_t)B_ * S_ * 64 * 4 + 256;
    if (ws_size < NEED) return;

    short* ws  = (short*)d_ws;
    short* qb  = ws;
    short* kb  = qb + SZ;
    short* vb  = kb + SZ;
    short* wqb = vb + SZ;
    short* wkb = wqb + DD;
    short* wvb = wkb + DD;
    short* wob = wvb + DD;
    short* Qp  = wob + DD;
    short* Kp  = Qp + SZ;
    short* Vp  = Kp + SZ;
    uint32_t* mp = (uint32_t*)(Vp + SZ);
    float* lutg = (float*)(mp + (size_t)B_ * S_ * 64);
    short* Vtr = qb;            // alias: qb dead after Q-GEMM
    short* Opx = kb;            // alias: kb dead after K-GEMM

    dim3 blk(256);
    cast_qkv<<<dim3(3 * 2048), blk, 0, stream>>>(q, k, v, qb, kb, vb);
    cast_w4<<<dim3(4 * 512), blk, 0, stream>>>(wq, wk, wv, wo, wqb, wkb, wvb, wob);
    pack_mask<<<dim3((unsigned)((size_t)B_ * S_ * S_ / 4 / 256)), blk, 0, stream>>>(mk, mp, lutg);

    gemm3_nt<<<dim3(D_ / 128, B_ * S_ / 128, 3), blk, 0, stream>>>(
        qb, wqb, Qp, kb, wkb, Kp, vb, wvb, Vp);

    transpose_v<<<dim3(B_ * H_ * (S_ / 64)), blk, 0, stream>>>(Vp, Vtr);

    attn_kernel<<<dim3(32, 32), blk, 0, stream>>>(Qp, Kp, Vtr, mp, lutg, Opx);

    gemm_out<<<dim3(D_ / 128, B_ * S_ / 128), blk, 0, stream>>>(Opx, wob, (float*)d_out);
}

// Round 6
// 169.036 us; speedup vs baseline: 1.5858x; 1.0156x over previous
//
#include <hip/hip_runtime.h>
#include <stdint.h>

#define B_ 2
#define S_ 2048
#define D_ 1024
#define H_ 16
#define DK_ 64

typedef __attribute__((ext_vector_type(8))) short short8;   // 8 x bf16 (raw bits)
typedef __attribute__((ext_vector_type(4))) float f32x4;

__device__ __forceinline__ short f2bf(float f) {
    uint32_t u = __float_as_uint(f);
    return (short)((u + 0x7FFFu + ((u >> 16) & 1u)) >> 16);
}

__device__ __forceinline__ float fexp2(float x) {
    float r;
    asm("v_exp_f32 %0, %1" : "=v"(r) : "v"(x));
    return r;
}

__device__ __forceinline__ uint32_t cvt_pk_bf16(float lo, float hi) {
    uint32_t r;
    asm("v_cvt_pk_bf16_f32 %0, %1, %2" : "=v"(r) : "v"(lo), "v"(hi));
    return r;
}

#define GLOAD16(gptr, lptr)                                                      \
    __builtin_amdgcn_global_load_lds(                                            \
        (const __attribute__((address_space(1))) void*)(gptr),                   \
        (__attribute__((address_space(3))) void*)(lptr), 16, 0, 0)

// ---------------- fused prep: casts + mask pack + LUT ----------------
// grid: [0,6144) cast qkv; [6144,8192) cast weights; [8192,16384) pack mask.
__global__ __launch_bounds__(256) void prep(const float* __restrict__ q,
                                            const float* __restrict__ k,
                                            const float* __restrict__ v,
                                            const float* __restrict__ wq,
                                            const float* __restrict__ wk,
                                            const float* __restrict__ wv,
                                            const float* __restrict__ wo,
                                            const int* __restrict__ mask,
                                            short* __restrict__ qb, short* __restrict__ kb,
                                            short* __restrict__ vb,
                                            short* __restrict__ wqb, short* __restrict__ wkb,
                                            short* __restrict__ wvb, short* __restrict__ wob,
                                            uint32_t* __restrict__ packed,
                                            float* __restrict__ lut) {
    int bid = blockIdx.x;
    int tid = threadIdx.x;
    if (bid < 8192) {
        const float* in;
        short* out;
        int i;
        if (bid < 6144) {
            int sel = bid >> 11;
            i = (bid & 2047) * 256 + tid;
            in = (sel == 0) ? q : (sel == 1) ? k : v;
            out = (sel == 0) ? qb : (sel == 1) ? kb : vb;
        } else {
            int idx = bid - 6144;
            int sel = idx >> 9;
            i = (idx & 511) * 256 + tid;
            in = (sel == 0) ? wq : (sel == 1) ? wk : (sel == 2) ? wv : wo;
            out = (sel == 0) ? wqb : (sel == 1) ? wkb : (sel == 2) ? wvb : wob;
            if (idx == 0 && tid < 64) {
                int e = tid >> 2, r = tid & 3;
                lut[tid] = ((e >> r) & 1) ? 0.0f : -8.0e9f;   // raw-score bias (x0.125 => -1e9)
            }
        }
        const float4* p = ((const float4*)in) + (size_t)i * 2;
        float4 x = p[0], y = p[1];
        short8 o;
        o[0] = f2bf(x.x); o[1] = f2bf(x.y); o[2] = f2bf(x.z); o[3] = f2bf(x.w);
        o[4] = f2bf(y.x); o[5] = f2bf(y.y); o[6] = f2bf(y.z); o[7] = f2bf(y.w);
        *(((short8*)out) + i) = o;
    } else {
        size_t t = (size_t)(bid - 8192) * 256 + tid;   // covers 4 mask elems
        int4 m = ((const int4*)mask)[t];
        uint32_t nib = (m.x != 0 ? 1u : 0u) | (m.y != 0 ? 2u : 0u) |
                       (m.z != 0 ? 4u : 0u) | (m.w != 0 ? 8u : 0u);
        int lane = tid & 63;
        uint32_t vv = nib << ((lane & 7) * 4);
        vv |= __shfl_xor(vv, 1);
        vv |= __shfl_xor(vv, 2);
        vv |= __shfl_xor(vv, 4);
        if ((lane & 7) == 0) packed[t >> 3] = vv;
    }
}

// ---------------- GEMM body: C[M,N] = A * W^T, 128x128 tile, BK=32 ----------------
// grid must be (8, 32[, z]); XCD-chunked swizzle: each XCD gets 4 M-rows x 8 N-cols.
#define GEMM_BODY(A, W, C, F32OUT, Mv, Nv, Kv)                                              \
    __shared__ short As[128 * 32];                                                          \
    __shared__ short Bs[128 * 32];                                                          \
    const int tid = threadIdx.x;                                                            \
    const int lane = tid & 63;                                                              \
    const int w = tid >> 6;                                                                 \
    const int wm = w >> 1, wn = w & 1;                                                      \
    const int l_ = blockIdx.x + (blockIdx.y << 3);                                          \
    const int xcd_ = l_ & 7, ii_ = l_ >> 3;                                                 \
    const int mBase = ((xcd_ << 2) + (ii_ >> 3)) * 128;                                     \
    const int nBase = (ii_ & 7) * 128;                                                      \
    f32x4 acc[4][4];                                                                        \
    _Pragma("unroll") for (int i = 0; i < 4; i++)                                           \
        _Pragma("unroll") for (int j = 0; j < 4; j++) acc[i][j] = (f32x4)0.f;               \
    const int srow = lane >> 2;                                                             \
    const int sslot = lane & 3;                                                             \
    for (int k0 = 0; k0 < Kv; k0 += 32) {                                                   \
        _Pragma("unroll") for (int i = 0; i < 2; ++i) {                                     \
            int seg = w * 2 + i;                                                            \
            int row = seg * 16 + srow;                                                      \
            const short* ga = A + (size_t)(mBase + row) * Kv + k0 + sslot * 8;              \
            GLOAD16(ga, (char*)As + seg * 1024);                                            \
            const short* gb = W + (size_t)(nBase + row) * Kv + k0 + sslot * 8;              \
            GLOAD16(gb, (char*)Bs + seg * 1024);                                            \
        }                                                                                   \
        asm volatile("s_waitcnt vmcnt(0)" ::: "memory");                                    \
        __syncthreads();                                                                    \
        short8 af[4], bfv[4];                                                               \
        _Pragma("unroll") for (int mi = 0; mi < 4; mi++)                                    \
            af[mi] = *(const short8*)&As[(wm * 64 + mi * 16 + (lane & 15)) * 32 + (lane >> 4) * 8]; \
        _Pragma("unroll") for (int ni = 0; ni < 4; ni++)                                    \
            bfv[ni] = *(const short8*)&Bs[(wn * 64 + ni * 16 + (lane & 15)) * 32 + (lane >> 4) * 8]; \
        _Pragma("unroll") for (int mi = 0; mi < 4; mi++)                                    \
            _Pragma("unroll") for (int ni = 0; ni < 4; ni++)                                \
                acc[mi][ni] = __builtin_amdgcn_mfma_f32_16x16x32_bf16(af[mi], bfv[ni], acc[mi][ni], 0, 0, 0); \
        __syncthreads();                                                                    \
    }                                                                                       \
    _Pragma("unroll") for (int mi = 0; mi < 4; mi++)                                        \
        _Pragma("unroll") for (int ni = 0; ni < 4; ni++)                                    \
            _Pragma("unroll") for (int r = 0; r < 4; r++) {                                 \
                int row = mBase + wm * 64 + mi * 16 + (lane >> 4) * 4 + r;                  \
                int col = nBase + wn * 64 + ni * 16 + (lane & 15);                          \
                float v = acc[mi][ni][r];                                                   \
                if (F32OUT) ((float*)C)[(size_t)row * Nv + col] = v;                        \
                else        ((short*)C)[(size_t)row * Nv + col] = f2bf(v);                  \
            }

__global__ __launch_bounds__(256) void gemm3_nt(const short* __restrict__ A0, const short* __restrict__ W0, short* __restrict__ C0,
                                                const short* __restrict__ A1, const short* __restrict__ W1, short* __restrict__ C1,
                                                const short* __restrict__ A2, const short* __restrict__ W2, short* __restrict__ C2) {
    const int z = blockIdx.z;
    const short* A = (z == 0) ? A0 : (z == 1) ? A1 : A2;
    const short* W = (z == 0) ? W0 : (z == 1) ? W1 : W2;
    short* C = (z == 0) ? C0 : (z == 1) ? C1 : C2;
    GEMM_BODY(A, W, C, 0, (B_ * S_), D_, D_)
}

__global__ __launch_bounds__(256) void gemm_out(const short* __restrict__ A,
                                                const short* __restrict__ W,
                                                float* __restrict__ C) {
    GEMM_BODY(A, W, C, 1, (B_ * S_), D_, D_)
}

// ---------------- V transpose ----------------
__global__ __launch_bounds__(256) void transpose_v(const short* __restrict__ Vp,
                                                   short* __restrict__ Vt) {
    __shared__ short t[64 * 72];
    int bid = blockIdx.x;
    int bh = bid >> 5;
    int st = bid & 31;
    int b = bh >> 4, h = bh & 15;
    int sBase = st * 64;
    int tid = threadIdx.x;
#pragma unroll
    for (int i = 0; i < 2; i++) {
        int ci = i * 256 + tid;
        int sr = ci >> 3, sl = ci & 7;
        short8 v = *(const short8*)&Vp[(size_t)(b * S_ + sBase + sr) * D_ + h * 64 + sl * 8];
#pragma unroll
        for (int j = 0; j < 8; j++) t[(sl * 8 + j) * 72 + sr] = v[j];
    }
    __syncthreads();
#pragma unroll
    for (int i = 0; i < 2; i++) {
        int ci = i * 256 + tid;
        int dk = ci >> 3, sl = ci & 7;
        short8 o = *(const short8*)&t[dk * 72 + sl * 8];
        *(short8*)&Vt[(size_t)((b * H_ + h) * 64 + dk) * S_ + sBase + sl * 8] = o;
    }
}

// ---------------- flash attention, KVBLK=128 fused softmax ----------------
// grid (32,32) swizzled; 4 waves; wave w owns q rows [qBase+w*16,+16); lane li owns q row li.
__global__ __launch_bounds__(256) void attn_kernel(const short* __restrict__ Qp,
                                                   const short* __restrict__ Kp,
                                                   const short* __restrict__ Vt,
                                                   const uint32_t* __restrict__ mp,
                                                   const float* __restrict__ lutg,
                                                   short* __restrict__ Op) {
    __shared__ short Ks[2][2][64 * 64];   // [dbuf][sub-tile][row*64+col]
    __shared__ short Vs[2][2][64 * 64];
    // XCD-chunked: each XCD owns 4 consecutive bh
    const int l_ = blockIdx.x + (blockIdx.y << 5);
    const int bh = ((l_ & 7) << 2) + (l_ >> 8);
    const int qt = (l_ >> 3) & 31;
    const int b = bh >> 4, h = bh & 15;
    const int qBase = qt * 64;
    const int tid = threadIdx.x, lane = tid & 63, w = tid >> 6;
    const int lg = lane >> 4;
    const int li = lane & 15;
    const float c1 = 0.18033688011112042f;   // 0.125 * log2(e)

    const int q = qBase + w * 16 + li;

    short8 qf[2];
#pragma unroll
    for (int ks = 0; ks < 2; ks++)
        qf[ks] = *(const short8*)&Qp[(size_t)(b * S_ + q) * D_ + h * 64 + lg * 8 + ks * 32];

    // staging: dest = linear tid*16 per wave-line, source pre-swizzled
    const int r0 = tid >> 3, sl = tid & 7;
    const int gs = sl ^ (r0 & 7);
    const short* kgb = Kp + ((size_t)(b * S_) + r0) * D_ + h * 64 + gs * 8;   // + krow*D
    const short* vgb = Vt + ((size_t)bh * 64 + r0) * S_ + gs * 8;             // + kcol
    const uint32_t* mrow = mp + ((size_t)(b * S_) + q) * 64;
    char* ldsK = (char*)&Ks[0][0][0];
    char* ldsV = (char*)&Vs[0][0][0];
    const int woff = w * 1024;

    // prologue: stage pair 0 into buffer 0
#pragma unroll
    for (int st = 0; st < 2; st++) {
        GLOAD16(kgb + (size_t)(st * 64) * D_, ldsK + st * 8192 + woff);
        GLOAD16(kgb + (size_t)(st * 64 + 32) * D_, ldsK + st * 8192 + 4096 + woff);
        GLOAD16(vgb + st * 64, ldsV + st * 8192 + woff);
        GLOAD16(vgb + st * 64 + (size_t)32 * S_, ldsV + st * 8192 + 4096 + woff);
    }
    uint4 mw4 = *(const uint4*)mrow;
    asm volatile("s_waitcnt vmcnt(0)" ::: "memory");
    __syncthreads();

    float m_r = -1e30f, l_r = 0.f;
    f32x4 acc[4];
#pragma unroll
    for (int g = 0; g < 4; g++) acc[g] = (f32x4)0.f;

    int cur = 0;

    for (int kt = 0; kt < S_ / 128; ++kt) {
        // mask bias LUT loads FIRST (so their waitcnt doesn't drain the prefetch queue)
        uint32_t mwarr[4] = {mw4.x, mw4.y, mw4.z, mw4.w};
        f32x4 msk[8];
#pragma unroll
        for (int nt = 0; nt < 8; nt++) {
            uint32_t wd = mwarr[nt >> 1];
            uint32_t nib = (wd >> (((nt & 1) << 4) + (lg << 2))) & 0xFu;
            msk[nt] = *(const f32x4*)&lutg[nib * 4];
        }

        uint4 mwn;
        if (kt < S_ / 128 - 1) {   // async prefetch of next 128-pair
            const int boff = (cur ^ 1) * 16384 + woff;
#pragma unroll
            for (int st = 0; st < 2; st++) {
                const size_t kr = (size_t)((kt + 1) * 128 + st * 64);
                GLOAD16(kgb + kr * D_, ldsK + boff + st * 8192);
                GLOAD16(kgb + (kr + 32) * D_, ldsK + boff + st * 8192 + 4096);
                GLOAD16(vgb + kr, ldsV + boff + st * 8192);
                GLOAD16(vgb + kr + (size_t)32 * S_, ldsV + boff + st * 8192 + 4096);
            }
            mwn = *(const uint4*)&mrow[(kt + 1) * 4];
        }

        // S^T = K Q^T + mask_bias: lane holds S[k = nt*16 + lg*4 + r][q = li]
        f32x4 sc[8];
        __builtin_amdgcn_s_setprio(1);
#pragma unroll
        for (int st = 0; st < 2; st++)
#pragma unroll
            for (int ntl = 0; ntl < 4; ntl++) {
                f32x4 c = msk[st * 4 + ntl];
#pragma unroll
                for (int ks = 0; ks < 2; ks++) {
                    short8 kf = *(const short8*)&Ks[cur][st][(ntl * 16 + li) * 64 + (((lg + ks * 4) ^ (li & 7)) << 3)];
                    c = __builtin_amdgcn_mfma_f32_16x16x32_bf16(kf, qf[ks], c, 0, 0, 0);
                }
                sc[st * 4 + ntl] = c;
            }
        __builtin_amdgcn_s_setprio(0);

        // row max over 32 values (balanced tree, max3-fusable)
        float t0 = fmaxf(fmaxf(sc[0][0], sc[0][1]), fmaxf(sc[0][2], sc[0][3]));
        float t1 = fmaxf(fmaxf(sc[1][0], sc[1][1]), fmaxf(sc[1][2], sc[1][3]));
        float t2 = fmaxf(fmaxf(sc[2][0], sc[2][1]), fmaxf(sc[2][2], sc[2][3]));
        float t3 = fmaxf(fmaxf(sc[3][0], sc[3][1]), fmaxf(sc[3][2], sc[3][3]));
        float t4 = fmaxf(fmaxf(sc[4][0], sc[4][1]), fmaxf(sc[4][2], sc[4][3]));
        float t5 = fmaxf(fmaxf(sc[5][0], sc[5][1]), fmaxf(sc[5][2], sc[5][3]));
        float t6 = fmaxf(fmaxf(sc[6][0], sc[6][1]), fmaxf(sc[6][2], sc[6][3]));
        float t7 = fmaxf(fmaxf(sc[7][0], sc[7][1]), fmaxf(sc[7][2], sc[7][3]));
        float tm = fmaxf(fmaxf(fmaxf(t0, t1), fmaxf(t2, t3)),
                         fmaxf(fmaxf(t4, t5), fmaxf(t6, t7)));
        tm = fmaxf(tm, __shfl_xor(tm, 16));
        tm = fmaxf(tm, __shfl_xor(tm, 32));

        // T13 defer-max
        if (__any((tm - m_r) * c1 > 10.0f)) {
            float mn = fmaxf(m_r, tm);
            float alpha = fexp2((m_r - mn) * c1);
            m_r = mn;
            l_r *= alpha;
#pragma unroll
            for (int g = 0; g < 4; g++) acc[g] *= alpha;
        }
        float mc = m_r * c1;

        // p = exp2(s*c1 - mc) (mask already in s); pack bf16 pairs
        uint32_t u[8][2];
        float ls = 0.f;
#pragma unroll
        for (int nt = 0; nt < 8; nt++) {
            float e0 = fexp2(__builtin_fmaf(sc[nt][0], c1, -mc));
            float e1 = fexp2(__builtin_fmaf(sc[nt][1], c1, -mc));
            float e2 = fexp2(__builtin_fmaf(sc[nt][2], c1, -mc));
            float e3 = fexp2(__builtin_fmaf(sc[nt][3], c1, -mc));
            ls += (e0 + e1) + (e2 + e3);
            u[nt][0] = cvt_pk_bf16(e0, e1);
            u[nt][1] = cvt_pk_bf16(e2, e3);
        }
        ls += __shfl_xor(ls, 16);
        ls += __shfl_xor(ls, 32);
        l_r += ls;

        // O^T += V^T P^T, in-register P redistribution (xor-16 exchange per ks)
        __builtin_amdgcn_s_setprio(1);
#pragma unroll
        for (int ks = 0; ks < 4; ks++) {
            const uint32_t s00 = u[2 * ks][0], s01 = u[2 * ks][1];
            const uint32_t s10 = u[2 * ks + 1][0], s11 = u[2 * ks + 1][1];
            uint32_t e0 = (lg & 1) ? s00 : s10;
            uint32_t e1 = (lg & 1) ? s01 : s11;
            uint32_t x0 = (uint32_t)__shfl_xor((int)e0, 16);
            uint32_t x1 = (uint32_t)__shfl_xor((int)e1, 16);
            union { uint32_t w4[4]; short8 s8; } pu;
            pu.w4[0] = (lg & 1) ? x0 : s00;
            pu.w4[1] = (lg & 1) ? x1 : s01;
            pu.w4[2] = (lg & 1) ? s10 : x0;
            pu.w4[3] = (lg & 1) ? s11 : x1;
            const int f = ks * 4 + ((lg & 1) << 1) + (lg >> 1);
            const int stv = f >> 3, fl = f & 7;
#pragma unroll
            for (int g = 0; g < 4; g++) {
                short8 vf = *(const short8*)&Vs[cur][stv][(g * 16 + li) * 64 + ((fl ^ (li & 7)) << 3)];
                acc[g] = __builtin_amdgcn_mfma_f32_16x16x32_bf16(vf, pu.s8, acc[g], 0, 0, 0);
            }
        }
        __builtin_amdgcn_s_setprio(0);

        asm volatile("s_waitcnt vmcnt(0)" ::: "memory");   // prefetch landed
        __syncthreads();
        cur ^= 1;
        if (kt < S_ / 128 - 1) mw4 = mwn;
    }

    // epilogue
    float inv = 1.f / l_r;
    short* orow = &Op[(size_t)(b * S_ + q) * D_ + h * 64];
#pragma unroll
    for (int g = 0; g < 4; g++) {
        uint2 o;
        o.x = cvt_pk_bf16(acc[g][0] * inv, acc[g][1] * inv);
        o.y = cvt_pk_bf16(acc[g][2] * inv, acc[g][3] * inv);
        *(uint2*)&orow[g * 16 + lg * 4] = o;
    }
}

extern "C" void kernel_launch(void* const* d_in, const int* in_sizes, int n_in,
                              void* d_out, int out_size, void* d_ws, size_t ws_size,
                              hipStream_t stream) {
    const float* q  = (const float*)d_in[0];
    const float* k  = (const float*)d_in[1];
    const float* v  = (const float*)d_in[2];
    const int*   mk = (const int*)d_in[3];
    const float* wq = (const float*)d_in[4];
    const float* wk = (const float*)d_in[5];
    const float* wv = (const float*)d_in[6];
    const float* wo = (const float*)d_in[7];

    const size_t SZ = (size_t)B_ * S_ * D_;
    const size_t DD = (size_t)D_ * D_;
    const size_t NEED = (6 * SZ + 4 * DD) * 2 + (size_t)B_ * S_ * 64 * 4 + 256;
    if (ws_size < NEED) return;

    short* ws  = (short*)d_ws;
    short* qb  = ws;
    short* kb  = qb + SZ;
    short* vb  = kb + SZ;
    short* wqb = vb + SZ;
    short* wkb = wqb + DD;
    short* wvb = wkb + DD;
    short* wob = wvb + DD;
    short* Qp  = wob + DD;
    short* Kp  = Qp + SZ;
    short* Vp  = Kp + SZ;
    uint32_t* mp = (uint32_t*)(Vp + SZ);
    float* lutg = (float*)(mp + (size_t)B_ * S_ * 64);
    short* Vtr = qb;            // alias: qb dead after Q-GEMM
    short* Opx = kb;            // alias: kb dead after K-GEMM

    dim3 blk(256);
    prep<<<dim3(16384), blk, 0, stream>>>(q, k, v, wq, wk, wv, wo, mk,
                                          qb, kb, vb, wqb, wkb, wvb, wob, mp, lutg);

    gemm3_nt<<<dim3(8, 32, 3), blk, 0, stream>>>(qb, wqb, Qp, kb, wkb, Kp, vb, wvb, Vp);

    transpose_v<<<dim3(B_ * H_ * (S_ / 64)), blk, 0, stream>>>(Vp, Vtr);

    attn_kernel<<<dim3(32, 32), blk, 0, stream>>>(Qp, Kp, Vtr, mp, lutg, Opx);

    gemm_out<<<dim3(8, 32), blk, 0, stream>>>(Opx, wob, (float*)d_out);
}